// Round 8
// baseline (171.776 us; speedup 1.0000x reference)
//
#include <hip/hip_runtime.h>
#include <cstdint>

// ---- types ----
typedef __bf16 bf16x8 __attribute__((ext_vector_type(8)));
typedef float  f32x4  __attribute__((ext_vector_type(4)));
typedef float  f32x16 __attribute__((ext_vector_type(16)));
typedef float  float8v __attribute__((ext_vector_type(8)));
typedef unsigned short ushort8v __attribute__((ext_vector_type(8)));
typedef unsigned short ushort4v __attribute__((ext_vector_type(4)));
typedef unsigned int   uint4v   __attribute__((ext_vector_type(4)));

__device__ __forceinline__ unsigned short f2b(float f) {
  uint32_t u = __builtin_bit_cast(uint32_t, f);
  u += 0x7FFFu + ((u >> 16) & 1u);     // round-to-nearest-even
  return (unsigned short)(u >> 16);
}
__device__ __forceinline__ float b2f(unsigned short h) {
  uint32_t u = ((uint32_t)h) << 16;
  return __builtin_bit_cast(float, u);
}
__device__ __forceinline__ unsigned int cvtpk(float lo, float hi_) {
  unsigned int r;
  asm("v_cvt_pk_bf16_f32 %0, %1, %2" : "=v"(r) : "v"(lo), "v"(hi_));
  return r;
}

__device__ __forceinline__ void async16(const void* g, void* l) {
  __builtin_amdgcn_global_load_lds(
      (const __attribute__((address_space(1))) void*)g,
      (__attribute__((address_space(3))) void*)l, 16, 0, 0);
}

// s_waitcnt immediates (gfx9 encoding): vmcnt[3:0]|[15:14], expcnt[6:4], lgkmcnt[11:8]
#define WAITVM(N)  __builtin_amdgcn_s_waitcnt(0x0F70 | ((N) & 15))

// ---- fused fp32 -> bf16 convert, 5 segments in one launch ----
struct CvtArgs {
  const float* src[5];
  unsigned short* dst[5];
  long n[5];
};
__global__ void cvt5_kernel(CvtArgs a) {
  long base = (long)blockIdx.x * blockDim.x + threadIdx.x;
  long gstride = (long)gridDim.x * blockDim.x;
#pragma unroll 1
  for (int sg = 0; sg < 5; ++sg) {
    const float* s = a.src[sg];
    unsigned short* d = a.dst[sg];
    long n8 = a.n[sg] >> 3;
    for (long i = base; i < n8; i += gstride) {
      float8v f = *(const float8v*)(s + i * 8);
      ushort8v o;
#pragma unroll
      for (int j = 0; j < 8; ++j) o[j] = f2b(f[j]);
      *(ushort8v*)(d + i * 8) = o;
    }
  }
}

// ---- 2-phase/K-tile GEMM: C[M][N] = A[M][K] * W[N][K]^T, K=2048 ----
// 8 waves (2m x 4n), 512 threads. One phase per k-half (32): read 8 A-frags +
// NF B-frags once, 32 (or 16) MFMAs per barrier-pair. 4-slot staging ring
// (pair index mod 4), lead 3 pairs, counted vmcnt. NO lgkmcnt drain: compiler
// emits fine-grained lgkmcnt per consuming MFMA -> LDS delivery overlaps the
// MFMA burst (slot p is all-waves-confirmed at phase p-1's WAITVM+barrier, so
// top-of-phase ds_reads are race-free; phase-entry sched_barrier(0) prevents
// hoisting above that confirm point).
template<bool F32OUT, int BM, int BN, int GX, int GY>
__global__ __launch_bounds__(512, 2)
void gemm2ph(const unsigned short* __restrict__ Ag, const unsigned short* __restrict__ Wg,
             void* __restrict__ Cp, int N) {
  constexpr int K = 2048;
  constexpr int MF = BM / 32;         // m-frags per wave (8 or 4)
  constexpr int NF = BN / 64;         // n-frags per wave (4)
  constexpr int AL = BM / 128;        // A gload instr per unit (2 or 1)
  constexpr int BL = BN / 128;        // B gload instr per unit (2)
  constexpr int IPP = AL + BL;        // instr per staged pair
  constexpr int ASLOT = BM * 64;      // bytes per A unit (rows x 32k x 2B)
  constexpr int BSLOT = BN * 64;
  constexpr int NWG = GX * GY;
  constexpr int CPX = NWG / 8;

  extern __shared__ char lds_c[];

  const int tid = threadIdx.x;
  const int wave = tid >> 6, lane = tid & 63;
  const int wm = wave >> 2, wn = wave & 3;
  const int lr = lane & 15, lg = lane >> 4;

  const int flat = blockIdx.y * GX + blockIdx.x;
  const int swz = (flat & 7) * CPX + (flat >> 3);
  const int m0 = (swz / GX) * BM, n0 = (swz % GX) * BN;

  const int laneSw = (lr >> 1) * 128 + (((((lr & 1) << 2) | lg) ^ (lr >> 1)) << 4);
  const int aoff = wm * (BM / 2) * 64 + laneSw;
  const int boff = wn * NF * 1024 + laneSw;

  f32x4 acc[MF][NF] = {};

  auto stageA = [&](int s) {
    char* slot = lds_c + (s & 3) * ASLOT;
    const int kc = s * 32;
#pragma unroll
    for (int j = 0; j < AL; ++j) {
      int q = (tid + 512 * j) * 16;
      int R = q >> 7, g2L = ((q >> 4) & 7) ^ (R & 7);
      int row = R * 2 + (g2L >> 2), kg = g2L & 3;
      async16(Ag + (size_t)(m0 + row) * K + kc + kg * 8, slot + q);
    }
  };
  auto stageB = [&](int s) {
    char* slot = lds_c + 4 * ASLOT + (s & 3) * BSLOT;
    const int kc = s * 32;
#pragma unroll
    for (int j = 0; j < BL; ++j) {
      int q = (tid + 512 * j) * 16;
      int R = q >> 7, g2L = ((q >> 4) & 7) ^ (R & 7);
      int row = R * 2 + (g2L >> 2), kg = g2L & 3;
      async16(Wg + (size_t)(n0 + row) * K + kc + kg * 8, slot + q);
    }
  };

#define PH(P, VM, DOST)                                                       \
  {                                                                           \
    __builtin_amdgcn_sched_barrier(0);                                        \
    const char* As_ = lds_c + ((P) & 3) * ASLOT;                              \
    const char* Bs_ = lds_c + 4 * ASLOT + ((P) & 3) * BSLOT;                  \
    bf16x8 af_[MF], bf_[NF];                                                  \
    _Pragma("unroll") for (int mi = 0; mi < MF; ++mi)                         \
      af_[mi] = *(const bf16x8*)(As_ + aoff + mi * 1024);                     \
    _Pragma("unroll") for (int ni = 0; ni < NF; ++ni)                         \
      bf_[ni] = *(const bf16x8*)(Bs_ + boff + ni * 1024);                     \
    if (DOST) { stageA((P) + 3); stageB((P) + 3); }                           \
    WAITVM(VM);                                                               \
    __builtin_amdgcn_s_barrier();                                             \
    __builtin_amdgcn_s_setprio(1);                                            \
    _Pragma("unroll") for (int mi = 0; mi < MF; ++mi)                         \
      _Pragma("unroll") for (int ni = 0; ni < NF; ++ni)                       \
        acc[mi][ni] = __builtin_amdgcn_mfma_f32_16x16x32_bf16(                \
            af_[mi], bf_[ni], acc[mi][ni], 0, 0, 0);                          \
    __builtin_amdgcn_s_setprio(0);                                            \
    __builtin_amdgcn_s_barrier();                                             \
  }

  // prologue: stage pairs 0..2, confirm pair 0
  stageA(0); stageB(0);
  stageA(1); stageB(1);
  stageA(2); stageB(2);
  WAITVM(2 * IPP);
  __builtin_amdgcn_s_barrier();

  for (int p2 = 0; p2 < 60; p2 += 4) {
    PH(p2 + 0, 2 * IPP, true);
    PH(p2 + 1, 2 * IPP, true);
    PH(p2 + 2, 2 * IPP, true);
    PH(p2 + 3, 2 * IPP, true);
  }
  PH(60, 2 * IPP, true);    // stages pair 63
  PH(61, IPP, false);
  PH(62, 0, false);
  PH(63, 0, false);
#undef PH

  // epilogue: C/D layout col=lane&15, row=(lane>>4)*4+j
#pragma unroll
  for (int mig = 0; mig < MF; ++mig) {
#pragma unroll
    for (int j = 0; j < 4; ++j) {
      int row = m0 + wm * (BM / 2) + mig * 16 + lg * 4 + j;
#pragma unroll
      for (int ni = 0; ni < NF; ++ni) {
        int col = n0 + wn * (NF * 16) + ni * 16 + lr;
        float v = acc[mig][ni][j];
        if (F32OUT) ((float*)Cp)[(size_t)row * N + col] = v;
        else        ((unsigned short*)Cp)[(size_t)row * N + col] = f2b(v);
      }
    }
  }
}

// ---- fused K-RoPE (in place) + V transpose -> vt[b][kvh][d=64][t=1024] ----
__global__ __launch_bounds__(256)
void ropekv_kernel(unsigned short* __restrict__ qkv,
                   const float* __restrict__ cosb, const float* __restrict__ sinb,
                   unsigned short* __restrict__ vt) {
  const int tt0 = blockIdx.x * 64;
  const int kvh = blockIdx.y;
  const int b   = blockIdx.z;
  const int tid = threadIdx.x;

  {
    int r = tid >> 2, c0 = (tid & 3) * 16;
    int t = tt0 + r;
    unsigned short* kp = qkv + (size_t)(b * 1024 + t) * 3072 + 2048 + kvh * 64 + c0;
    const float* cb = cosb + t * 32 + c0 / 2;
    const float* sb = sinb + t * 32 + c0 / 2;
    ushort8v x0 = *(const ushort8v*)kp;
    ushort8v x1 = *(const ushort8v*)(kp + 8);
    float8v c = *(const float8v*)cb;
    float8v s = *(const float8v*)sb;
    ushort8v o0, o1;
#pragma unroll
    for (int j = 0; j < 4; ++j) {
      float xr = b2f(x0[2 * j]), xi = b2f(x0[2 * j + 1]);
      o0[2 * j]     = f2b(xr * c[j] - xi * s[j]);
      o0[2 * j + 1] = f2b(xr * s[j] + xi * c[j]);
    }
#pragma unroll
    for (int j = 0; j < 4; ++j) {
      float xr = b2f(x1[2 * j]), xi = b2f(x1[2 * j + 1]);
      o1[2 * j]     = f2b(xr * c[4 + j] - xi * s[4 + j]);
      o1[2 * j + 1] = f2b(xr * s[4 + j] + xi * c[4 + j]);
    }
    *(ushort8v*)kp = o0;
    *(ushort8v*)(kp + 8) = o1;
  }

  __shared__ unsigned short lT[64 * 68];
#pragma unroll
  for (int i = 0; i < 2; ++i) {
    int r = i * 32 + (tid >> 3), c = (tid & 7) * 8;
    const unsigned short* src = qkv + (size_t)(b * 1024 + tt0 + r) * 3072 + 2560 + kvh * 64 + c;
    ushort8v v = *(const ushort8v*)src;
    ushort4v a, b4;
#pragma unroll
    for (int j = 0; j < 4; ++j) { a[j] = v[j]; b4[j] = v[j + 4]; }
    *(ushort4v*)&lT[r * 68 + c]     = a;
    *(ushort4v*)&lT[r * 68 + c + 4] = b4;
  }
  __syncthreads();
#pragma unroll
  for (int i = 0; i < 2; ++i) {
    int d = tid & 63;
    int tt = i * 4 + (tid >> 6);
    ushort8v o;
#pragma unroll
    for (int j = 0; j < 8; ++j) o[j] = lT[(tt * 8 + j) * 68 + d];
    *(ushort8v*)&vt[((size_t)((b * 8 + kvh) * 64 + d)) * 1024 + tt0 + tt * 8] = o;
  }
}

// ---- flash attention: paired q-tiles processed SEQUENTIALLY (one live state) ----
__global__ __launch_bounds__(256, 2)
void attn_kernel(const unsigned short* __restrict__ qkv, const unsigned short* __restrict__ vt,
                 const float* __restrict__ cosb, const float* __restrict__ sinb,
                 unsigned short* __restrict__ ob) {
  const int flat = (blockIdx.z * 8 + blockIdx.y) * 16 + blockIdx.x;
  const int swzb = (flat & 7) * 64 + (flat >> 3);
  const int bx = swzb & 15, kvh = (swzb >> 4) & 7, b = swzb >> 7;

  const int tid = threadIdx.x, wave = tid >> 6, lane = tid & 63;
  const int l31 = lane & 31, hi = lane >> 5;
  const int h = kvh * 4 + wave;

  const int qth = 31 - bx, qtl = bx;
  const int q0h = qth * 32, q0l = qtl * 32;
  const int nth = qth / 4 + 1, ntl = qtl / 4 + 1;
  const int ntot = nth + ntl;

  __shared__ unsigned short lK[2][128 * 64];
  __shared__ unsigned short lVt[2][64 * 128];

  auto ldq = [&](int q0, bf16x8* qf) {
    int t = q0 + l31;
    const unsigned short* qp = qkv + (size_t)(b * 1024 + t) * 3072 + h * 64;
#pragma unroll
    for (int dk = 0; dk < 4; ++dk) {
      ushort8v q = *(const ushort8v*)(qp + dk * 16 + hi * 8);
      f32x4 c4 = *(const f32x4*)(cosb + t * 32 + dk * 8 + hi * 4);
      f32x4 s4 = *(const f32x4*)(sinb + t * 32 + dk * 8 + hi * 4);
      ushort8v o;
#pragma unroll
      for (int j = 0; j < 4; ++j) {
        float xr = b2f(q[2 * j]), xi = b2f(q[2 * j + 1]);
        o[2 * j]     = f2b(xr * c4[j] - xi * s4[j]);
        o[2 * j + 1] = f2b(xr * s4[j] + xi * c4[j]);
      }
      qf[dk] = __builtin_bit_cast(bf16x8, o);
    }
  };

  const unsigned short* kg = qkv + (size_t)(b * 1024) * 3072 + 2048 + kvh * 64;
  const unsigned short* vg = vt + (size_t)(b * 8 + kvh) * 64 * 1024;

  auto stage = [&](int kvb, int bi) {
    const int sr  = tid >> 3;
    const int scb = (tid & 7) * 16;
#pragma unroll
    for (int i = 0; i < 4; ++i) {
      int r = i * 32 + sr;
      int cb = scb ^ ((r & 7) << 4);
      async16(kg + (size_t)(kvb + r) * 3072 + (cb >> 1), &lK[bi][r * 64 + (scb >> 1)]);
    }
    const int rv0 = tid >> 4;
    const int scv = (tid & 15) * 16;
#pragma unroll
    for (int i = 0; i < 4; ++i) {
      int rv = i * 16 + rv0;
      int cbv = scv ^ ((rv & 15) << 4);
      async16(vg + (size_t)rv * 1024 + kvb + (cbv >> 1), &lVt[bi][rv * 128 + (scv >> 1)]);
    }
  };

  bf16x8 qf[4];
  f32x16 oacc[2] = {};
  float m2 = -3e38f, l_run = 0.f;
  int q0 = q0h;

  ldq(q0h, qf);

  const float SC = 0.125f * 1.44269504f;

  auto chunk64 = [&](int cur, int ckvb, int c, bool lastT) {
    f32x16 sd[2] = {};
    __builtin_amdgcn_s_setprio(1);
#pragma unroll
    for (int s = 0; s < 2; ++s) {
      const int krow = c * 64 + s * 32 + l31;
      const char* kr = (const char*)lK[cur] + krow * 128;
      const int swz = (krow & 7) << 4;
#pragma unroll
      for (int dk = 0; dk < 4; ++dk) {
        bf16x8 kf = *(const bf16x8*)(kr + ((dk * 32 + hi * 16) ^ swz));
        sd[s] = __builtin_amdgcn_mfma_f32_32x32x16_bf16(kf, qf[dk], sd[s], 0, 0, 0);
      }
    }
    __builtin_amdgcn_s_setprio(0);

#pragma unroll
    for (int s = 0; s < 2; ++s)
#pragma unroll
      for (int r = 0; r < 16; ++r) {
        float v = sd[s][r] * SC;
        if (lastT) {
          int kvg = ckvb + s * 32 + (r & 3) + 8 * (r >> 2) + 4 * hi;
          if (kvg > q0 + l31) v = -3e38f;
        }
        sd[s][r] = v;
      }
    float pm = sd[0][0];
#pragma unroll
    for (int s = 0; s < 2; ++s)
#pragma unroll
      for (int r = 0; r < 16; ++r) pm = fmaxf(pm, sd[s][r]);
    pm = fmaxf(pm, __shfl_xor(pm, 32));
    if (!__all(pm <= m2 + 11.0f)) {          // T13 defer-max (log2 domain)
      float mnew = fmaxf(m2, pm);
      float alpha = exp2f(m2 - mnew);
      m2 = mnew;
      l_run *= alpha;
#pragma unroll
      for (int db = 0; db < 2; ++db)
#pragma unroll
        for (int r = 0; r < 16; ++r) oacc[db][r] *= alpha;
    }
    float tsum = 0.f;
#pragma unroll
    for (int s = 0; s < 2; ++s)
#pragma unroll
      for (int r = 0; r < 16; ++r) { float p = exp2f(sd[s][r] - m2); sd[s][r] = p; tsum += p; }
    tsum += __shfl_xor(tsum, 32);
    l_run += tsum;

    bf16x8 pf[2][2];
#pragma unroll
    for (int s = 0; s < 2; ++s)
#pragma unroll
      for (int kc = 0; kc < 2; ++kc) {
        unsigned int cA = cvtpk(sd[s][8 * kc + 0], sd[s][8 * kc + 1]);
        unsigned int cB = cvtpk(sd[s][8 * kc + 4], sd[s][8 * kc + 5]);
        unsigned int cC = cvtpk(sd[s][8 * kc + 2], sd[s][8 * kc + 3]);
        unsigned int cD = cvtpk(sd[s][8 * kc + 6], sd[s][8 * kc + 7]);
        unsigned int xA = __shfl_xor(cA, 32), xB = __shfl_xor(cB, 32);
        unsigned int xC = __shfl_xor(cC, 32), xD = __shfl_xor(cD, 32);
        uint4v u;
        u[0] = hi ? xB : cA;
        u[1] = hi ? xD : cC;
        u[2] = hi ? cB : xA;
        u[3] = hi ? cD : xC;
        pf[s][kc] = __builtin_bit_cast(bf16x8, u);
      }

    __builtin_amdgcn_s_setprio(1);
#pragma unroll
    for (int db = 0; db < 2; ++db) {
      const int row = db * 32 + l31;
      const char* vr = (const char*)lVt[cur] + row * 256;
      const int vswz = (row & 15) << 4;
#pragma unroll
      for (int s = 0; s < 2; ++s)
#pragma unroll
        for (int kc = 0; kc < 2; ++kc) {
          bf16x8 vf = *(const bf16x8*)(vr + ((c * 128 + s * 64 + kc * 32 + hi * 16) ^ vswz));
          oacc[db] = __builtin_amdgcn_mfma_f32_32x32x16_bf16(vf, pf[s][kc], oacc[db], 0, 0, 0);
        }
    }
    __builtin_amdgcn_s_setprio(0);
  };

  auto writeOut = [&](int q0w) {
    float inv = 1.0f / l_run;
    unsigned short* orow = ob + (size_t)(b * 1024 + q0w + l31) * 2048 + h * 64;
#pragma unroll
    for (int db = 0; db < 2; ++db)
#pragma unroll
      for (int g = 0; g < 4; ++g) {
        int d0 = db * 32 + 8 * g + 4 * hi;
        ushort4v o;
#pragma unroll
        for (int j = 0; j < 4; ++j) o[j] = f2b(oacc[db][4 * g + j] * inv);
        *(ushort4v*)(orow + d0) = o;
      }
  };

  auto kvb_of = [&](int j) { return (j < nth ? j : j - nth) * 128; };

  stage(0, 0);
  __syncthreads();

  for (int j = 0; j < ntot; ++j) {
    const int cur = j & 1;
    if (j + 1 < ntot) stage(kvb_of(j + 1), cur ^ 1);   // issue-early (T14)
    const int kvb = kvb_of(j);
    const bool lastT = (j == nth - 1) || (j == ntot - 1);

#pragma unroll 1
    for (int c = 0; c < 2; ++c) {
      if (kvb + c * 64 > q0 + 31) continue;   // fully-masked chunk (uniform)
      chunk64(cur, kvb + c * 64, c, lastT);
    }

    if (j == nth - 1) {                        // hi pass done -> switch to lo
      writeOut(q0h);
      oacc[0] = f32x16{}; oacc[1] = f32x16{};
      m2 = -3e38f; l_run = 0.f;
      q0 = q0l;
      ldq(q0l, qf);
    }
    __syncthreads();   // drains prefetch + buffer handoff
  }
  writeOut(q0l);
}

extern "C" void kernel_launch(void* const* d_in, const int* in_sizes, int n_in,
                              void* d_out, int out_size, void* d_ws, size_t ws_size,
                              hipStream_t stream) {
  const float* input = (const float*)d_in[0];
  const float* fcos  = (const float*)d_in[1];
  const float* fsin  = (const float*)d_in[2];
  const float* wq = (const float*)d_in[4];
  const float* wk = (const float*)d_in[5];
  const float* wv = (const float*)d_in[6];
  const float* wo = (const float*)d_in[7];
  float* out = (float*)d_out;

  unsigned short* xb   = (unsigned short*)d_ws;               // 4096 x 2048 (dead after gemm1)
  unsigned short* wqkv = xb + (size_t)4096 * 2048;            // 3072 x 2048
  unsigned short* wob  = wqkv + (size_t)3072 * 2048;          // 2048 x 2048
  unsigned short* qkv  = wob + (size_t)2048 * 2048;           // 4096 x 3072
  unsigned short* ob   = qkv + (size_t)4096 * 3072;           // 4096 x 2048
  unsigned short* vtb  = xb;                                  // 4*8*64*1024 (reuses xb)

  hipFuncSetAttribute((const void*)&gemm2ph<false, 256, 256, 12, 16>,
                      hipFuncAttributeMaxDynamicSharedMemorySize, 131072);
  hipFuncSetAttribute((const void*)&gemm2ph<true, 128, 256, 8, 32>,
                      hipFuncAttributeMaxDynamicSharedMemorySize, 98304);

  CvtArgs ca;
  ca.src[0] = input; ca.dst[0] = xb;                        ca.n[0] = (long)4096 * 2048;
  ca.src[1] = wq;    ca.dst[1] = wqkv;                      ca.n[1] = (long)2048 * 2048;
  ca.src[2] = wk;    ca.dst[2] = wqkv + (size_t)2048 * 2048; ca.n[2] = (long)512 * 2048;
  ca.src[3] = wv;    ca.dst[3] = wqkv + (size_t)2560 * 2048; ca.n[3] = (long)512 * 2048;
  ca.src[4] = wo;    ca.dst[4] = wob;                       ca.n[4] = (long)2048 * 2048;
  hipLaunchKernelGGL(cvt5_kernel, dim3(2048), dim3(256), 0, stream, ca);

  // fused QKV projection: qkv = xb @ wqkv^T  (M=4096, N=3072, K=2048)
  hipLaunchKernelGGL((gemm2ph<false, 256, 256, 12, 16>), dim3(12, 16), dim3(512), 131072,
                     stream, xb, wqkv, (void*)qkv, 3072);

  // K-RoPE in place + V transpose
  hipLaunchKernelGGL(ropekv_kernel, dim3(16, 8, 4), dim3(256), 0, stream,
                     qkv, fcos, fsin, vtb);

  // flash attention (Q-RoPE fused) -> ob (b,t,h,d) bf16
  hipLaunchKernelGGL(attn_kernel, dim3(16, 8, 4), dim3(256), 0, stream,
                     qkv, vtb, fcos, fsin, ob);

  // output projection: out = ob @ wob^T  (M=4096, N=2048, K=2048), fp32 out
  hipLaunchKernelGGL((gemm2ph<true, 128, 256, 8, 32>), dim3(8, 32), dim3(512), 98304,
                     stream, ob, wob, (void*)out, 2048);
}

// Round 9
// 169.930 us; speedup vs baseline: 1.0109x; 1.0109x over previous
//
#include <hip/hip_runtime.h>
#include <cstdint>

// ---- types ----
typedef __bf16 bf16x8 __attribute__((ext_vector_type(8)));
typedef float  f32x4  __attribute__((ext_vector_type(4)));
typedef float  f32x16 __attribute__((ext_vector_type(16)));
typedef float  float8v __attribute__((ext_vector_type(8)));
typedef unsigned short ushort8v __attribute__((ext_vector_type(8)));
typedef unsigned short ushort4v __attribute__((ext_vector_type(4)));
typedef unsigned int   uint4v   __attribute__((ext_vector_type(4)));

__device__ __forceinline__ unsigned short f2b(float f) {
  uint32_t u = __builtin_bit_cast(uint32_t, f);
  u += 0x7FFFu + ((u >> 16) & 1u);     // round-to-nearest-even
  return (unsigned short)(u >> 16);
}
__device__ __forceinline__ float b2f(unsigned short h) {
  uint32_t u = ((uint32_t)h) << 16;
  return __builtin_bit_cast(float, u);
}
__device__ __forceinline__ unsigned int cvtpk(float lo, float hi_) {
  unsigned int r;
  asm("v_cvt_pk_bf16_f32 %0, %1, %2" : "=v"(r) : "v"(lo), "v"(hi_));
  return r;
}

__device__ __forceinline__ void async16(const void* g, void* l) {
  __builtin_amdgcn_global_load_lds(
      (const __attribute__((address_space(1))) void*)g,
      (__attribute__((address_space(3))) void*)l, 16, 0, 0);
}

// s_waitcnt immediates (gfx9 encoding): vmcnt[3:0]|[15:14], expcnt[6:4], lgkmcnt[11:8]
#define WAITVM(N)  __builtin_amdgcn_s_waitcnt(0x0F70 | ((N) & 15))

// ---- fused fp32 -> bf16 convert, 5 segments in one launch ----
struct CvtArgs {
  const float* src[5];
  unsigned short* dst[5];
  long n[5];
};
__global__ void cvt5_kernel(CvtArgs a) {
  long base = (long)blockIdx.x * blockDim.x + threadIdx.x;
  long gstride = (long)gridDim.x * blockDim.x;
#pragma unroll 1
  for (int sg = 0; sg < 5; ++sg) {
    const float* s = a.src[sg];
    unsigned short* d = a.dst[sg];
    long n8 = a.n[sg] >> 3;
    for (long i = base; i < n8; i += gstride) {
      float8v f = *(const float8v*)(s + i * 8);
      ushort8v o;
#pragma unroll
      for (int j = 0; j < 8; ++j) o[j] = f2b(f[j]);
      *(ushort8v*)(d + i * 8) = o;
    }
  }
}

// ---- interleaved-read GEMM: C[M][N] = A[M][K] * W[N][K]^T, K=2048 ----
// 8 waves (2m x 4n), 512 threads, one phase per k-half(32). Key: the ds_reads
// for phase p+1's fragments are issued INSIDE phase p's MFMA burst (slot p+1
// is confirmed by phase p's WAITVM+barrier, which precede the burst), so the
// LDS pipe (~1150 cyc/phase) drains under the matrix pipe (~1240 cyc/phase)
// instead of serializing with it. 4-slot ring, stage lead 3, counted vmcnt.
template<bool F32OUT, int BM, int BN, int GX, int GY>
__global__ __launch_bounds__(512, 2)
void gemmIL(const unsigned short* __restrict__ Ag, const unsigned short* __restrict__ Wg,
            void* __restrict__ Cp, int N) {
  constexpr int K = 2048;
  constexpr int MF = BM / 32;         // m-frags per wave (8 or 4)
  constexpr int NF = BN / 64;         // n-frags per wave (4)
  constexpr int AL = BM / 128;        // A gload instr per thread per pair
  constexpr int BL = BN / 128;        // B gload instr per thread per pair
  constexpr int IPP = AL + BL;        // instr per staged pair
  constexpr int ASLOT = BM * 64;      // bytes per A slot
  constexpr int BSLOT = BN * 64;
  constexpr int NWG = GX * GY;
  constexpr int CPX = NWG / 8;

  extern __shared__ char lds_c[];

  const int tid = threadIdx.x;
  const int wave = tid >> 6, lane = tid & 63;
  const int wm = wave >> 2, wn = wave & 3;
  const int lr = lane & 15, lg = lane >> 4;

  const int flat = blockIdx.y * GX + blockIdx.x;
  const int swz = (flat & 7) * CPX + (flat >> 3);
  const int m0 = (swz / GX) * BM, n0 = (swz % GX) * BN;

  const int laneSw = (lr >> 1) * 128 + (((((lr & 1) << 2) | lg) ^ (lr >> 1)) << 4);
  const int aoff = wm * (BM / 2) * 64 + laneSw;
  const int boff = wn * NF * 1024 + laneSw;

  f32x4 acc[MF][NF] = {};
  bf16x8 af[MF], bf[NF];

  auto stageA = [&](int s) {
    char* slot = lds_c + (s & 3) * ASLOT;
    const int kc = s * 32;
#pragma unroll
    for (int j = 0; j < AL; ++j) {
      int q = (tid + 512 * j) * 16;
      int R = q >> 7, g2L = ((q >> 4) & 7) ^ (R & 7);
      int row = R * 2 + (g2L >> 2), kg = g2L & 3;
      async16(Ag + (size_t)(m0 + row) * K + kc + kg * 8, slot + q);
    }
  };
  auto stageB = [&](int s) {
    char* slot = lds_c + 4 * ASLOT + (s & 3) * BSLOT;
    const int kc = s * 32;
#pragma unroll
    for (int j = 0; j < BL; ++j) {
      int q = (tid + 512 * j) * 16;
      int R = q >> 7, g2L = ((q >> 4) & 7) ^ (R & 7);
      int row = R * 2 + (g2L >> 2), kg = g2L & 3;
      async16(Wg + (size_t)(n0 + row) * K + kc + kg * 8, slot + q);
    }
  };

#define PH(P, VM, DOST, DORD)                                                 \
  {                                                                           \
    if (DOST) { stageA((P) + 3); stageB((P) + 3); }                           \
    WAITVM(VM);                                                               \
    __builtin_amdgcn_s_barrier();                                             \
    __builtin_amdgcn_sched_barrier(0);                                        \
    const char* Asn_ = lds_c + (((P) + 1) & 3) * ASLOT;                       \
    const char* Bsn_ = lds_c + 4 * ASLOT + (((P) + 1) & 3) * BSLOT;           \
    __builtin_amdgcn_s_setprio(1);                                            \
    _Pragma("unroll") for (int mi = 0; mi < MF; ++mi) {                       \
      _Pragma("unroll") for (int ni = 0; ni < NF; ++ni)                       \
        acc[mi][ni] = __builtin_amdgcn_mfma_f32_16x16x32_bf16(                \
            af[mi], bf[ni], acc[mi][ni], 0, 0, 0);                            \
      if (DORD) af[mi] = *(const bf16x8*)(Asn_ + aoff + mi * 1024);           \
    }                                                                         \
    if (DORD) {                                                               \
      _Pragma("unroll") for (int ni = 0; ni < NF; ++ni)                       \
        bf[ni] = *(const bf16x8*)(Bsn_ + boff + ni * 1024);                   \
    }                                                                         \
    __builtin_amdgcn_s_setprio(0);                                            \
    __builtin_amdgcn_sched_barrier(0);                                        \
    __builtin_amdgcn_s_barrier();                                             \
  }

  // prologue: stage pairs 0..2, confirm pair 0, preload phase-0 fragments
  stageA(0); stageB(0);
  stageA(1); stageB(1);
  stageA(2); stageB(2);
  WAITVM(2 * IPP);
  __builtin_amdgcn_s_barrier();
  {
    const char* As0 = lds_c;
    const char* Bs0 = lds_c + 4 * ASLOT;
#pragma unroll
    for (int mi = 0; mi < MF; ++mi) af[mi] = *(const bf16x8*)(As0 + aoff + mi * 1024);
#pragma unroll
    for (int ni = 0; ni < NF; ++ni) bf[ni] = *(const bf16x8*)(Bs0 + boff + ni * 1024);
  }

  for (int p2 = 0; p2 < 60; p2 += 4) {
    PH(p2 + 0, 2 * IPP, true, true);
    PH(p2 + 1, 2 * IPP, true, true);
    PH(p2 + 2, 2 * IPP, true, true);
    PH(p2 + 3, 2 * IPP, true, true);
  }
  PH(60, 2 * IPP, true, true);    // stages pair 63
  PH(61, IPP, false, true);       // reads slot 62 (pair 62 landed)
  PH(62, 0, false, true);         // reads slot 63 (drained)
  PH(63, 0, false, false);
#undef PH

  // epilogue: C/D layout col=lane&15, row=(lane>>4)*4+j
#pragma unroll
  for (int mig = 0; mig < MF; ++mig) {
#pragma unroll
    for (int j = 0; j < 4; ++j) {
      int row = m0 + wm * (BM / 2) + mig * 16 + lg * 4 + j;
#pragma unroll
      for (int ni = 0; ni < NF; ++ni) {
        int col = n0 + wn * (NF * 16) + ni * 16 + lr;
        float v = acc[mig][ni][j];
        if (F32OUT) ((float*)Cp)[(size_t)row * N + col] = v;
        else        ((unsigned short*)Cp)[(size_t)row * N + col] = f2b(v);
      }
    }
  }
}

// ---- fused K-RoPE (in place) + V transpose -> vt[b][kvh][d=64][t=1024] ----
__global__ __launch_bounds__(256)
void ropekv_kernel(unsigned short* __restrict__ qkv,
                   const float* __restrict__ cosb, const float* __restrict__ sinb,
                   unsigned short* __restrict__ vt) {
  const int tt0 = blockIdx.x * 64;
  const int kvh = blockIdx.y;
  const int b   = blockIdx.z;
  const int tid = threadIdx.x;

  {
    int r = tid >> 2, c0 = (tid & 3) * 16;
    int t = tt0 + r;
    unsigned short* kp = qkv + (size_t)(b * 1024 + t) * 3072 + 2048 + kvh * 64 + c0;
    const float* cb = cosb + t * 32 + c0 / 2;
    const float* sb = sinb + t * 32 + c0 / 2;
    ushort8v x0 = *(const ushort8v*)kp;
    ushort8v x1 = *(const ushort8v*)(kp + 8);
    float8v c = *(const float8v*)cb;
    float8v s = *(const float8v*)sb;
    ushort8v o0, o1;
#pragma unroll
    for (int j = 0; j < 4; ++j) {
      float xr = b2f(x0[2 * j]), xi = b2f(x0[2 * j + 1]);
      o0[2 * j]     = f2b(xr * c[j] - xi * s[j]);
      o0[2 * j + 1] = f2b(xr * s[j] + xi * c[j]);
    }
#pragma unroll
    for (int j = 0; j < 4; ++j) {
      float xr = b2f(x1[2 * j]), xi = b2f(x1[2 * j + 1]);
      o1[2 * j]     = f2b(xr * c[4 + j] - xi * s[4 + j]);
      o1[2 * j + 1] = f2b(xr * s[4 + j] + xi * c[4 + j]);
    }
    *(ushort8v*)kp = o0;
    *(ushort8v*)(kp + 8) = o1;
  }

  __shared__ unsigned short lT[64 * 68];
#pragma unroll
  for (int i = 0; i < 2; ++i) {
    int r = i * 32 + (tid >> 3), c = (tid & 7) * 8;
    const unsigned short* src = qkv + (size_t)(b * 1024 + tt0 + r) * 3072 + 2560 + kvh * 64 + c;
    ushort8v v = *(const ushort8v*)src;
    ushort4v a, b4;
#pragma unroll
    for (int j = 0; j < 4; ++j) { a[j] = v[j]; b4[j] = v[j + 4]; }
    *(ushort4v*)&lT[r * 68 + c]     = a;
    *(ushort4v*)&lT[r * 68 + c + 4] = b4;
  }
  __syncthreads();
#pragma unroll
  for (int i = 0; i < 2; ++i) {
    int d = tid & 63;
    int tt = i * 4 + (tid >> 6);
    ushort8v o;
#pragma unroll
    for (int j = 0; j < 8; ++j) o[j] = lT[(tt * 8 + j) * 68 + d];
    *(ushort8v*)&vt[((size_t)((b * 8 + kvh) * 64 + d)) * 1024 + tt0 + tt * 8] = o;
  }
}

// ---- flash attention: paired q-tiles processed SEQUENTIALLY (one live state) ----
__global__ __launch_bounds__(256, 2)
void attn_kernel(const unsigned short* __restrict__ qkv, const unsigned short* __restrict__ vt,
                 const float* __restrict__ cosb, const float* __restrict__ sinb,
                 unsigned short* __restrict__ ob) {
  const int flat = (blockIdx.z * 8 + blockIdx.y) * 16 + blockIdx.x;
  const int swzb = (flat & 7) * 64 + (flat >> 3);
  const int bx = swzb & 15, kvh = (swzb >> 4) & 7, b = swzb >> 7;

  const int tid = threadIdx.x, wave = tid >> 6, lane = tid & 63;
  const int l31 = lane & 31, hi = lane >> 5;
  const int h = kvh * 4 + wave;

  const int qth = 31 - bx, qtl = bx;
  const int q0h = qth * 32, q0l = qtl * 32;
  const int nth = qth / 4 + 1, ntl = qtl / 4 + 1;
  const int ntot = nth + ntl;

  __shared__ unsigned short lK[2][128 * 64];
  __shared__ unsigned short lVt[2][64 * 128];

  auto ldq = [&](int q0, bf16x8* qf) {
    int t = q0 + l31;
    const unsigned short* qp = qkv + (size_t)(b * 1024 + t) * 3072 + h * 64;
#pragma unroll
    for (int dk = 0; dk < 4; ++dk) {
      ushort8v q = *(const ushort8v*)(qp + dk * 16 + hi * 8);
      f32x4 c4 = *(const f32x4*)(cosb + t * 32 + dk * 8 + hi * 4);
      f32x4 s4 = *(const f32x4*)(sinb + t * 32 + dk * 8 + hi * 4);
      ushort8v o;
#pragma unroll
      for (int j = 0; j < 4; ++j) {
        float xr = b2f(q[2 * j]), xi = b2f(q[2 * j + 1]);
        o[2 * j]     = f2b(xr * c4[j] - xi * s4[j]);
        o[2 * j + 1] = f2b(xr * s4[j] + xi * c4[j]);
      }
      qf[dk] = __builtin_bit_cast(bf16x8, o);
    }
  };

  const unsigned short* kg = qkv + (size_t)(b * 1024) * 3072 + 2048 + kvh * 64;
  const unsigned short* vg = vt + (size_t)(b * 8 + kvh) * 64 * 1024;

  auto stage = [&](int kvb, int bi) {
    const int sr  = tid >> 3;
    const int scb = (tid & 7) * 16;
#pragma unroll
    for (int i = 0; i < 4; ++i) {
      int r = i * 32 + sr;
      int cb = scb ^ ((r & 7) << 4);
      async16(kg + (size_t)(kvb + r) * 3072 + (cb >> 1), &lK[bi][r * 64 + (scb >> 1)]);
    }
    const int rv0 = tid >> 4;
    const int scv = (tid & 15) * 16;
#pragma unroll
    for (int i = 0; i < 4; ++i) {
      int rv = i * 16 + rv0;
      int cbv = scv ^ ((rv & 15) << 4);
      async16(vg + (size_t)rv * 1024 + kvb + (cbv >> 1), &lVt[bi][rv * 128 + (scv >> 1)]);
    }
  };

  bf16x8 qf[4];
  f32x16 oacc[2] = {};
  float m2 = -3e38f, l_run = 0.f;
  int q0 = q0h;

  ldq(q0h, qf);

  const float SC = 0.125f * 1.44269504f;

  auto chunk64 = [&](int cur, int ckvb, int c, bool lastT) {
    f32x16 sd[2] = {};
    __builtin_amdgcn_s_setprio(1);
#pragma unroll
    for (int s = 0; s < 2; ++s) {
      const int krow = c * 64 + s * 32 + l31;
      const char* kr = (const char*)lK[cur] + krow * 128;
      const int swz = (krow & 7) << 4;
#pragma unroll
      for (int dk = 0; dk < 4; ++dk) {
        bf16x8 kf = *(const bf16x8*)(kr + ((dk * 32 + hi * 16) ^ swz));
        sd[s] = __builtin_amdgcn_mfma_f32_32x32x16_bf16(kf, qf[dk], sd[s], 0, 0, 0);
      }
    }
    __builtin_amdgcn_s_setprio(0);

#pragma unroll
    for (int s = 0; s < 2; ++s)
#pragma unroll
      for (int r = 0; r < 16; ++r) {
        float v = sd[s][r] * SC;
        if (lastT) {
          int kvg = ckvb + s * 32 + (r & 3) + 8 * (r >> 2) + 4 * hi;
          if (kvg > q0 + l31) v = -3e38f;
        }
        sd[s][r] = v;
      }
    float pm = sd[0][0];
#pragma unroll
    for (int s = 0; s < 2; ++s)
#pragma unroll
      for (int r = 0; r < 16; ++r) pm = fmaxf(pm, sd[s][r]);
    pm = fmaxf(pm, __shfl_xor(pm, 32));
    if (!__all(pm <= m2 + 11.0f)) {          // T13 defer-max (log2 domain)
      float mnew = fmaxf(m2, pm);
      float alpha = exp2f(m2 - mnew);
      m2 = mnew;
      l_run *= alpha;
#pragma unroll
      for (int db = 0; db < 2; ++db)
#pragma unroll
        for (int r = 0; r < 16; ++r) oacc[db][r] *= alpha;
    }
    float tsum = 0.f;
#pragma unroll
    for (int s = 0; s < 2; ++s)
#pragma unroll
      for (int r = 0; r < 16; ++r) { float p = exp2f(sd[s][r] - m2); sd[s][r] = p; tsum += p; }
    tsum += __shfl_xor(tsum, 32);
    l_run += tsum;

    bf16x8 pf[2][2];
#pragma unroll
    for (int s = 0; s < 2; ++s)
#pragma unroll
      for (int kc = 0; kc < 2; ++kc) {
        unsigned int cA = cvtpk(sd[s][8 * kc + 0], sd[s][8 * kc + 1]);
        unsigned int cB = cvtpk(sd[s][8 * kc + 4], sd[s][8 * kc + 5]);
        unsigned int cC = cvtpk(sd[s][8 * kc + 2], sd[s][8 * kc + 3]);
        unsigned int cD = cvtpk(sd[s][8 * kc + 6], sd[s][8 * kc + 7]);
        unsigned int xA = __shfl_xor(cA, 32), xB = __shfl_xor(cB, 32);
        unsigned int xC = __shfl_xor(cC, 32), xD = __shfl_xor(cD, 32);
        uint4v u;
        u[0] = hi ? xB : cA;
        u[1] = hi ? xD : cC;
        u[2] = hi ? cB : xA;
        u[3] = hi ? cD : xC;
        pf[s][kc] = __builtin_bit_cast(bf16x8, u);
      }

    __builtin_amdgcn_s_setprio(1);
#pragma unroll
    for (int db = 0; db < 2; ++db) {
      const int row = db * 32 + l31;
      const char* vr = (const char*)lVt[cur] + row * 256;
      const int vswz = (row & 15) << 4;
#pragma unroll
      for (int s = 0; s < 2; ++s)
#pragma unroll
        for (int kc = 0; kc < 2; ++kc) {
          bf16x8 vf = *(const bf16x8*)(vr + ((c * 128 + s * 64 + kc * 32 + hi * 16) ^ vswz));
          oacc[db] = __builtin_amdgcn_mfma_f32_32x32x16_bf16(vf, pf[s][kc], oacc[db], 0, 0, 0);
        }
    }
    __builtin_amdgcn_s_setprio(0);
  };

  auto writeOut = [&](int q0w) {
    float inv = 1.0f / l_run;
    unsigned short* orow = ob + (size_t)(b * 1024 + q0w + l31) * 2048 + h * 64;
#pragma unroll
    for (int db = 0; db < 2; ++db)
#pragma unroll
      for (int g = 0; g < 4; ++g) {
        int d0 = db * 32 + 8 * g + 4 * hi;
        ushort4v o;
#pragma unroll
        for (int j = 0; j < 4; ++j) o[j] = f2b(oacc[db][4 * g + j] * inv);
        *(ushort4v*)(orow + d0) = o;
      }
  };

  auto kvb_of = [&](int j) { return (j < nth ? j : j - nth) * 128; };

  stage(0, 0);
  __syncthreads();

  for (int j = 0; j < ntot; ++j) {
    const int cur = j & 1;
    if (j + 1 < ntot) stage(kvb_of(j + 1), cur ^ 1);   // issue-early (T14)
    const int kvb = kvb_of(j);
    const bool lastT = (j == nth - 1) || (j == ntot - 1);

#pragma unroll 1
    for (int c = 0; c < 2; ++c) {
      if (kvb + c * 64 > q0 + 31) continue;   // fully-masked chunk (uniform)
      chunk64(cur, kvb + c * 64, c, lastT);
    }

    if (j == nth - 1) {                        // hi pass done -> switch to lo
      writeOut(q0h);
      oacc[0] = f32x16{}; oacc[1] = f32x16{};
      m2 = -3e38f; l_run = 0.f;
      q0 = q0l;
      ldq(q0l, qf);
    }
    __syncthreads();   // drains prefetch + buffer handoff
  }
  writeOut(q0l);
}

extern "C" void kernel_launch(void* const* d_in, const int* in_sizes, int n_in,
                              void* d_out, int out_size, void* d_ws, size_t ws_size,
                              hipStream_t stream) {
  const float* input = (const float*)d_in[0];
  const float* fcos  = (const float*)d_in[1];
  const float* fsin  = (const float*)d_in[2];
  const float* wq = (const float*)d_in[4];
  const float* wk = (const float*)d_in[5];
  const float* wv = (const float*)d_in[6];
  const float* wo = (const float*)d_in[7];
  float* out = (float*)d_out;

  unsigned short* xb   = (unsigned short*)d_ws;               // 4096 x 2048 (dead after gemm1)
  unsigned short* wqkv = xb + (size_t)4096 * 2048;            // 3072 x 2048
  unsigned short* wob  = wqkv + (size_t)3072 * 2048;          // 2048 x 2048
  unsigned short* qkv  = wob + (size_t)2048 * 2048;           // 4096 x 3072
  unsigned short* ob   = qkv + (size_t)4096 * 3072;           // 4096 x 2048
  unsigned short* vtb  = xb;                                  // 4*8*64*1024 (reuses xb)

  hipFuncSetAttribute((const void*)&gemmIL<false, 256, 256, 12, 16>,
                      hipFuncAttributeMaxDynamicSharedMemorySize, 131072);
  hipFuncSetAttribute((const void*)&gemmIL<true, 128, 256, 8, 32>,
                      hipFuncAttributeMaxDynamicSharedMemorySize, 98304);

  CvtArgs ca;
  ca.src[0] = input; ca.dst[0] = xb;                        ca.n[0] = (long)4096 * 2048;
  ca.src[1] = wq;    ca.dst[1] = wqkv;                      ca.n[1] = (long)2048 * 2048;
  ca.src[2] = wk;    ca.dst[2] = wqkv + (size_t)2048 * 2048; ca.n[2] = (long)512 * 2048;
  ca.src[3] = wv;    ca.dst[3] = wqkv + (size_t)2560 * 2048; ca.n[3] = (long)512 * 2048;
  ca.src[4] = wo;    ca.dst[4] = wob;                       ca.n[4] = (long)2048 * 2048;
  hipLaunchKernelGGL(cvt5_kernel, dim3(2048), dim3(256), 0, stream, ca);

  // fused QKV projection: qkv = xb @ wqkv^T  (M=4096, N=3072, K=2048)
  hipLaunchKernelGGL((gemmIL<false, 256, 256, 12, 16>), dim3(12, 16), dim3(512), 131072,
                     stream, xb, wqkv, (void*)qkv, 3072);

  // K-RoPE in place + V transpose
  hipLaunchKernelGGL(ropekv_kernel, dim3(16, 8, 4), dim3(256), 0, stream,
                     qkv, fcos, fsin, vtb);

  // flash attention (Q-RoPE fused) -> ob (b,t,h,d) bf16
  hipLaunchKernelGGL(attn_kernel, dim3(16, 8, 4), dim3(256), 0, stream,
                     qkv, vtb, fcos, fsin, ob);

  // output projection: out = ob @ wob^T  (M=4096, N=2048, K=2048), fp32 out
  hipLaunchKernelGGL((gemmIL<true, 128, 256, 8, 32>), dim3(8, 32), dim3(512), 98304,
                     stream, ob, wob, (void*)out, 2048);
}

// Round 10
// 168.266 us; speedup vs baseline: 1.0209x; 1.0099x over previous
//
#include <hip/hip_runtime.h>
#include <cstdint>

// ---- types ----
typedef __bf16 bf16x8 __attribute__((ext_vector_type(8)));
typedef float  f32x4  __attribute__((ext_vector_type(4)));
typedef float  f32x16 __attribute__((ext_vector_type(16)));
typedef float  float8v __attribute__((ext_vector_type(8)));
typedef unsigned short ushort8v __attribute__((ext_vector_type(8)));
typedef unsigned short ushort4v __attribute__((ext_vector_type(4)));
typedef unsigned int   uint4v   __attribute__((ext_vector_type(4)));

__device__ __forceinline__ unsigned short f2b(float f) {
  uint32_t u = __builtin_bit_cast(uint32_t, f);
  u += 0x7FFFu + ((u >> 16) & 1u);     // round-to-nearest-even
  return (unsigned short)(u >> 16);
}
__device__ __forceinline__ float b2f(unsigned short h) {
  uint32_t u = ((uint32_t)h) << 16;
  return __builtin_bit_cast(float, u);
}
__device__ __forceinline__ unsigned int cvtpk(float lo, float hi_) {
  unsigned int r;
  asm("v_cvt_pk_bf16_f32 %0, %1, %2" : "=v"(r) : "v"(lo), "v"(hi_));
  return r;
}

__device__ __forceinline__ void async16(const void* g, void* l) {
  __builtin_amdgcn_global_load_lds(
      (const __attribute__((address_space(1))) void*)g,
      (__attribute__((address_space(3))) void*)l, 16, 0, 0);
}

// s_waitcnt immediates (gfx9 encoding): vmcnt[3:0]|[15:14], expcnt[6:4], lgkmcnt[11:8]
#define WAITVM(N)  __builtin_amdgcn_s_waitcnt(0x0F70 | ((N) & 15))

// ---- fused fp32 -> bf16 convert, 5 segments in one launch ----
struct CvtArgs {
  const float* src[5];
  unsigned short* dst[5];
  long n[5];
};
__global__ void cvt5_kernel(CvtArgs a) {
  long base = (long)blockIdx.x * blockDim.x + threadIdx.x;
  long gstride = (long)gridDim.x * blockDim.x;
#pragma unroll 1
  for (int sg = 0; sg < 5; ++sg) {
    const float* s = a.src[sg];
    unsigned short* d = a.dst[sg];
    long n8 = a.n[sg] >> 3;
    for (long i = base; i < n8; i += gstride) {
      float8v f = *(const float8v*)(s + i * 8);
      ushort8v o;
#pragma unroll
      for (int j = 0; j < 8; ++j) o[j] = f2b(f[j]);
      *(ushort8v*)(d + i * 8) = o;
    }
  }
}

// ---- 8-phase GEMM (m201 template): C[M][N] = A[M][K] * W[N][K]^T, K=2048 ----
// BM=256, BK=64, 8 waves (2m x 4n), 512 threads. 4 phases per K-tile:
// (m-lo,k0)(m-hi,k0)(m-lo,k1)(m-hi,k1), 16 (or 8) MFMA each; B-frags reused in
// registers across the two m-phases (reads/phase: 8,4,8,4). One 2-gload stage
// unit per phase into a 4-slot k-half ring (dbuf=2). vmcnt ONCE per K-tile
// (counted, never 0 until tail): at tile T's phi3, allowed outstanding =
// {B(2T+4), A(2T+4), B(2T+5)} = 2BL+AL loads, which confirms through A(2T+3) —
// exactly what tile T+1 reads. Slot-overwrite audit: every unit is staged >=1
// phase-end barrier after its slot's last in-phase read (reads are consumed by
// MFMA in-phase, so lgkm-drained before the issuing wave reaches the barrier).
template<bool F32OUT, int BN, int GX, int GY>
__global__ __launch_bounds__(512, 2)
void gemm8p(const unsigned short* __restrict__ Ag, const unsigned short* __restrict__ Wg,
            void* __restrict__ Cp, int N) {
  constexpr int K = 2048;
  constexpr int BM = 256;
  constexpr int NF = BN / 64;         // n-frags per wave (4 or 2)
  constexpr int AL = 2;               // A gloads per thread per unit
  constexpr int BL = BN / 128;        // B gloads per thread per unit (2 or 1)
  constexpr int VMS = 2 * BL + AL;    // steady-state counted vmcnt (6 or 4)
  constexpr int ASLOT = BM * 64;      // 16KB: 256 rows x 32k x 2B
  constexpr int BSLOT = BN * 64;
  constexpr int NWG = GX * GY;
  constexpr int CPX = NWG / 8;

  extern __shared__ char lds_c[];

  const int tid = threadIdx.x;
  const int wave = tid >> 6, lane = tid & 63;
  const int wm = wave >> 2, wn = wave & 3;
  const int lr = lane & 15, lg = lane >> 4;

  const int flat = blockIdx.y * GX + blockIdx.x;
  const int swz = (flat & 7) * CPX + (flat >> 3);
  const int m0 = (swz / GX) * BM, n0 = (swz % GX) * BN;

  const int laneSw = (lr >> 1) * 128 + (((((lr & 1) << 2) | lg) ^ (lr >> 1)) << 4);
  const int aoff = wm * 128 * 64 + laneSw;
  const int boff = wn * NF * 1024 + laneSw;

  f32x4 acc[8][NF] = {};
  bf16x8 af[4], bf[NF];

  auto stA = [&](int slot, int s) {
    char* sl = lds_c + slot * ASLOT;
    const int kc = s * 32;
#pragma unroll
    for (int j = 0; j < AL; ++j) {
      int q = (tid + 512 * j) * 16;
      int R = q >> 7, g2L = ((q >> 4) & 7) ^ (R & 7);
      int row = R * 2 + (g2L >> 2), kg = g2L & 3;
      async16(Ag + (size_t)(m0 + row) * K + kc + kg * 8, sl + q);
    }
  };
  auto stB = [&](int slot, int s) {
    char* sl = lds_c + 4 * ASLOT + slot * BSLOT;
    const int kc = s * 32;
#pragma unroll
    for (int j = 0; j < BL; ++j) {
      int q = (tid + 512 * j) * 16;
      int R = q >> 7, g2L = ((q >> 4) & 7) ^ (R & 7);
      int row = R * 2 + (g2L >> 2), kg = g2L & 3;
      async16(Wg + (size_t)(n0 + row) * K + kc + kg * 8, sl + q);
    }
  };

  // One phase: in-phase frag reads -> stage one unit -> [vmcnt] -> barrier ->
  // MFMA burst -> barrier. VM = -1: no wait.
#define PH(RSLOT, MH, RDB, STG, VM)                                           \
  {                                                                           \
    const char* As_ = lds_c + (RSLOT) * ASLOT;                                \
    _Pragma("unroll") for (int mi = 0; mi < 4; ++mi)                          \
      af[mi] = *(const bf16x8*)(As_ + aoff + ((MH) * 4 + mi) * 1024);         \
    if (RDB) {                                                                \
      const char* Bs_ = lds_c + 4 * ASLOT + (RSLOT) * BSLOT;                  \
      _Pragma("unroll") for (int ni = 0; ni < NF; ++ni)                       \
        bf[ni] = *(const bf16x8*)(Bs_ + boff + ni * 1024);                    \
    }                                                                         \
    STG;                                                                      \
    if ((VM) >= 0) WAITVM(VM);                                                \
    __builtin_amdgcn_s_barrier();                                             \
    __builtin_amdgcn_s_setprio(1);                                            \
    _Pragma("unroll") for (int mi = 0; mi < 4; ++mi)                          \
      _Pragma("unroll") for (int ni = 0; ni < NF; ++ni)                       \
        acc[(MH) * 4 + mi][ni] = __builtin_amdgcn_mfma_f32_16x16x32_bf16(     \
            af[mi], bf[ni], acc[(MH) * 4 + mi][ni], 0, 0, 0);                 \
    __builtin_amdgcn_s_setprio(0);                                            \
    __builtin_amdgcn_s_barrier();                                             \
  }

  // prologue: units B0,A0,B1,A1,B2,A2,B3 (issue order = steady order);
  // confirm tile 0's needs (B0,A0,B1,A1), leave B2,A2,B3 in flight.
  stB(0, 0); stA(0, 0); stB(1, 1); stA(1, 1); stB(2, 2); stA(2, 2); stB(3, 3);
  WAITVM(VMS);
  __builtin_amdgcn_s_barrier();

  // main: 15 iters x 2 K-tiles (T even + odd), full staging
  for (int T = 0; T < 30; T += 2) {
    const int p0 = 2 * T;
    // tile T (even): reads slots 0 (k0), 1 (k1)
    PH(0, 0, true,  stA(3, p0 + 3), -1);
    PH(0, 1, false, stB(0, p0 + 4), -1);
    PH(1, 0, true,  stA(0, p0 + 4), -1);
    PH(1, 1, false, stB(1, p0 + 5), VMS);
    // tile T+1 (odd): reads slots 2, 3
    PH(2, 0, true,  stA(1, p0 + 5), -1);
    PH(2, 1, false, stB(2, p0 + 6), -1);
    PH(3, 0, true,  stA(2, p0 + 6), -1);
    PH(3, 1, false, stB(3, p0 + 7), VMS);
  }
  // tile 30: stage last unit A(63); drain at its phi3
  PH(0, 0, true,  stA(3, 63), -1);
  PH(0, 1, false, (void)0, -1);
  PH(1, 0, true,  (void)0, -1);
  PH(1, 1, false, (void)0, 0);
  // tile 31: pure compute
  PH(2, 0, true,  (void)0, -1);
  PH(2, 1, false, (void)0, -1);
  PH(3, 0, true,  (void)0, -1);
  PH(3, 1, false, (void)0, -1);
#undef PH

  // epilogue: C/D layout col=lane&15, row=(lane>>4)*4+j
#pragma unroll
  for (int mig = 0; mig < 8; ++mig) {
#pragma unroll
    for (int j = 0; j < 4; ++j) {
      int row = m0 + wm * 128 + mig * 16 + lg * 4 + j;
#pragma unroll
      for (int ni = 0; ni < NF; ++ni) {
        int col = n0 + wn * (NF * 16) + ni * 16 + lr;
        float v = acc[mig][ni][j];
        if (F32OUT) ((float*)Cp)[(size_t)row * N + col] = v;
        else        ((unsigned short*)Cp)[(size_t)row * N + col] = f2b(v);
      }
    }
  }
}

// ---- fused K-RoPE (in place) + V transpose -> vt[b][kvh][d=64][t=1024] ----
__global__ __launch_bounds__(256)
void ropekv_kernel(unsigned short* __restrict__ qkv,
                   const float* __restrict__ cosb, const float* __restrict__ sinb,
                   unsigned short* __restrict__ vt) {
  const int tt0 = blockIdx.x * 64;
  const int kvh = blockIdx.y;
  const int b   = blockIdx.z;
  const int tid = threadIdx.x;

  {
    int r = tid >> 2, c0 = (tid & 3) * 16;
    int t = tt0 + r;
    unsigned short* kp = qkv + (size_t)(b * 1024 + t) * 3072 + 2048 + kvh * 64 + c0;
    const float* cb = cosb + t * 32 + c0 / 2;
    const float* sb = sinb + t * 32 + c0 / 2;
    ushort8v x0 = *(const ushort8v*)kp;
    ushort8v x1 = *(const ushort8v*)(kp + 8);
    float8v c = *(const float8v*)cb;
    float8v s = *(const float8v*)sb;
    ushort8v o0, o1;
#pragma unroll
    for (int j = 0; j < 4; ++j) {
      float xr = b2f(x0[2 * j]), xi = b2f(x0[2 * j + 1]);
      o0[2 * j]     = f2b(xr * c[j] - xi * s[j]);
      o0[2 * j + 1] = f2b(xr * s[j] + xi * c[j]);
    }
#pragma unroll
    for (int j = 0; j < 4; ++j) {
      float xr = b2f(x1[2 * j]), xi = b2f(x1[2 * j + 1]);
      o1[2 * j]     = f2b(xr * c[4 + j] - xi * s[4 + j]);
      o1[2 * j + 1] = f2b(xr * s[4 + j] + xi * c[4 + j]);
    }
    *(ushort8v*)kp = o0;
    *(ushort8v*)(kp + 8) = o1;
  }

  __shared__ unsigned short lT[64 * 68];
#pragma unroll
  for (int i = 0; i < 2; ++i) {
    int r = i * 32 + (tid >> 3), c = (tid & 7) * 8;
    const unsigned short* src = qkv + (size_t)(b * 1024 + tt0 + r) * 3072 + 2560 + kvh * 64 + c;
    ushort8v v = *(const ushort8v*)src;
    ushort4v a, b4;
#pragma unroll
    for (int j = 0; j < 4; ++j) { a[j] = v[j]; b4[j] = v[j + 4]; }
    *(ushort4v*)&lT[r * 68 + c]     = a;
    *(ushort4v*)&lT[r * 68 + c + 4] = b4;
  }
  __syncthreads();
#pragma unroll
  for (int i = 0; i < 2; ++i) {
    int d = tid & 63;
    int tt = i * 4 + (tid >> 6);
    ushort8v o;
#pragma unroll
    for (int j = 0; j < 8; ++j) o[j] = lT[(tt * 8 + j) * 68 + d];
    *(ushort8v*)&vt[((size_t)((b * 8 + kvh) * 64 + d)) * 1024 + tt0 + tt * 8] = o;
  }
}

// ---- flash attention: paired q-tiles processed SEQUENTIALLY (one live state) ----
__global__ __launch_bounds__(256, 2)
void attn_kernel(const unsigned short* __restrict__ qkv, const unsigned short* __restrict__ vt,
                 const float* __restrict__ cosb, const float* __restrict__ sinb,
                 unsigned short* __restrict__ ob) {
  const int flat = (blockIdx.z * 8 + blockIdx.y) * 16 + blockIdx.x;
  const int swzb = (flat & 7) * 64 + (flat >> 3);
  const int bx = swzb & 15, kvh = (swzb >> 4) & 7, b = swzb >> 7;

  const int tid = threadIdx.x, wave = tid >> 6, lane = tid & 63;
  const int l31 = lane & 31, hi = lane >> 5;
  const int h = kvh * 4 + wave;

  const int qth = 31 - bx, qtl = bx;
  const int q0h = qth * 32, q0l = qtl * 32;
  const int nth = qth / 4 + 1, ntl = qtl / 4 + 1;
  const int ntot = nth + ntl;

  __shared__ unsigned short lK[2][128 * 64];
  __shared__ unsigned short lVt[2][64 * 128];

  auto ldq = [&](int q0, bf16x8* qf) {
    int t = q0 + l31;
    const unsigned short* qp = qkv + (size_t)(b * 1024 + t) * 3072 + h * 64;
#pragma unroll
    for (int dk = 0; dk < 4; ++dk) {
      ushort8v q = *(const ushort8v*)(qp + dk * 16 + hi * 8);
      f32x4 c4 = *(const f32x4*)(cosb + t * 32 + dk * 8 + hi * 4);
      f32x4 s4 = *(const f32x4*)(sinb + t * 32 + dk * 8 + hi * 4);
      ushort8v o;
#pragma unroll
      for (int j = 0; j < 4; ++j) {
        float xr = b2f(q[2 * j]), xi = b2f(q[2 * j + 1]);
        o[2 * j]     = f2b(xr * c4[j] - xi * s4[j]);
        o[2 * j + 1] = f2b(xr * s4[j] + xi * c4[j]);
      }
      qf[dk] = __builtin_bit_cast(bf16x8, o);
    }
  };

  const unsigned short* kg = qkv + (size_t)(b * 1024) * 3072 + 2048 + kvh * 64;
  const unsigned short* vg = vt + (size_t)(b * 8 + kvh) * 64 * 1024;

  auto stage = [&](int kvb, int bi) {
    const int sr  = tid >> 3;
    const int scb = (tid & 7) * 16;
#pragma unroll
    for (int i = 0; i < 4; ++i) {
      int r = i * 32 + sr;
      int cb = scb ^ ((r & 7) << 4);
      async16(kg + (size_t)(kvb + r) * 3072 + (cb >> 1), &lK[bi][r * 64 + (scb >> 1)]);
    }
    const int rv0 = tid >> 4;
    const int scv = (tid & 15) * 16;
#pragma unroll
    for (int i = 0; i < 4; ++i) {
      int rv = i * 16 + rv0;
      int cbv = scv ^ ((rv & 15) << 4);
      async16(vg + (size_t)rv * 1024 + kvb + (cbv >> 1), &lVt[bi][rv * 128 + (scv >> 1)]);
    }
  };

  bf16x8 qf[4];
  f32x16 oacc[2] = {};
  float m2 = -3e38f, l_run = 0.f;
  int q0 = q0h;

  ldq(q0h, qf);

  const float SC = 0.125f * 1.44269504f;

  auto chunk64 = [&](int cur, int ckvb, int c, bool lastT) {
    f32x16 sd[2] = {};
    __builtin_amdgcn_s_setprio(1);
#pragma unroll
    for (int s = 0; s < 2; ++s) {
      const int krow = c * 64 + s * 32 + l31;
      const char* kr = (const char*)lK[cur] + krow * 128;
      const int swz = (krow & 7) << 4;
#pragma unroll
      for (int dk = 0; dk < 4; ++dk) {
        bf16x8 kf = *(const bf16x8*)(kr + ((dk * 32 + hi * 16) ^ swz));
        sd[s] = __builtin_amdgcn_mfma_f32_32x32x16_bf16(kf, qf[dk], sd[s], 0, 0, 0);
      }
    }
    __builtin_amdgcn_s_setprio(0);

#pragma unroll
    for (int s = 0; s < 2; ++s)
#pragma unroll
      for (int r = 0; r < 16; ++r) {
        float v = sd[s][r] * SC;
        if (lastT) {
          int kvg = ckvb + s * 32 + (r & 3) + 8 * (r >> 2) + 4 * hi;
          if (kvg > q0 + l31) v = -3e38f;
        }
        sd[s][r] = v;
      }
    float pm = sd[0][0];
#pragma unroll
    for (int s = 0; s < 2; ++s)
#pragma unroll
      for (int r = 0; r < 16; ++r) pm = fmaxf(pm, sd[s][r]);
    pm = fmaxf(pm, __shfl_xor(pm, 32));
    if (!__all(pm <= m2 + 11.0f)) {          // T13 defer-max (log2 domain)
      float mnew = fmaxf(m2, pm);
      float alpha = exp2f(m2 - mnew);
      m2 = mnew;
      l_run *= alpha;
#pragma unroll
      for (int db = 0; db < 2; ++db)
#pragma unroll
        for (int r = 0; r < 16; ++r) oacc[db][r] *= alpha;
    }
    float tsum = 0.f;
#pragma unroll
    for (int s = 0; s < 2; ++s)
#pragma unroll
      for (int r = 0; r < 16; ++r) { float p = exp2f(sd[s][r] - m2); sd[s][r] = p; tsum += p; }
    tsum += __shfl_xor(tsum, 32);
    l_run += tsum;

    bf16x8 pf[2][2];
#pragma unroll
    for (int s = 0; s < 2; ++s)
#pragma unroll
      for (int kc = 0; kc < 2; ++kc) {
        unsigned int cA = cvtpk(sd[s][8 * kc + 0], sd[s][8 * kc + 1]);
        unsigned int cB = cvtpk(sd[s][8 * kc + 4], sd[s][8 * kc + 5]);
        unsigned int cC = cvtpk(sd[s][8 * kc + 2], sd[s][8 * kc + 3]);
        unsigned int cD = cvtpk(sd[s][8 * kc + 6], sd[s][8 * kc + 7]);
        unsigned int xA = __shfl_xor(cA, 32), xB = __shfl_xor(cB, 32);
        unsigned int xC = __shfl_xor(cC, 32), xD = __shfl_xor(cD, 32);
        uint4v u;
        u[0] = hi ? xB : cA;
        u[1] = hi ? xD : cC;
        u[2] = hi ? cB : xA;
        u[3] = hi ? cD : xC;
        pf[s][kc] = __builtin_bit_cast(bf16x8, u);
      }

    __builtin_amdgcn_s_setprio(1);
#pragma unroll
    for (int db = 0; db < 2; ++db) {
      const int row = db * 32 + l31;
      const char* vr = (const char*)lVt[cur] + row * 256;
      const int vswz = (row & 15) << 4;
#pragma unroll
      for (int s = 0; s < 2; ++s)
#pragma unroll
        for (int kc = 0; kc < 2; ++kc) {
          bf16x8 vf = *(const bf16x8*)(vr + ((c * 128 + s * 64 + kc * 32 + hi * 16) ^ vswz));
          oacc[db] = __builtin_amdgcn_mfma_f32_32x32x16_bf16(vf, pf[s][kc], oacc[db], 0, 0, 0);
        }
    }
    __builtin_amdgcn_s_setprio(0);
  };

  auto writeOut = [&](int q0w) {
    float inv = 1.0f / l_run;
    unsigned short* orow = ob + (size_t)(b * 1024 + q0w + l31) * 2048 + h * 64;
#pragma unroll
    for (int db = 0; db < 2; ++db)
#pragma unroll
      for (int g = 0; g < 4; ++g) {
        int d0 = db * 32 + 8 * g + 4 * hi;
        ushort4v o;
#pragma unroll
        for (int j = 0; j < 4; ++j) o[j] = f2b(oacc[db][4 * g + j] * inv);
        *(ushort4v*)(orow + d0) = o;
      }
  };

  auto kvb_of = [&](int j) { return (j < nth ? j : j - nth) * 128; };

  stage(0, 0);
  __syncthreads();

  for (int j = 0; j < ntot; ++j) {
    const int cur = j & 1;
    if (j + 1 < ntot) stage(kvb_of(j + 1), cur ^ 1);   // issue-early (T14)
    const int kvb = kvb_of(j);
    const bool lastT = (j == nth - 1) || (j == ntot - 1);

#pragma unroll 1
    for (int c = 0; c < 2; ++c) {
      if (kvb + c * 64 > q0 + 31) continue;   // fully-masked chunk (uniform)
      chunk64(cur, kvb + c * 64, c, lastT);
    }

    if (j == nth - 1) {                        // hi pass done -> switch to lo
      writeOut(q0h);
      oacc[0] = f32x16{}; oacc[1] = f32x16{};
      m2 = -3e38f; l_run = 0.f;
      q0 = q0l;
      ldq(q0l, qf);
    }
    __syncthreads();   // drains prefetch + buffer handoff
  }
  writeOut(q0l);
}

extern "C" void kernel_launch(void* const* d_in, const int* in_sizes, int n_in,
                              void* d_out, int out_size, void* d_ws, size_t ws_size,
                              hipStream_t stream) {
  const float* input = (const float*)d_in[0];
  const float* fcos  = (const float*)d_in[1];
  const float* fsin  = (const float*)d_in[2];
  const float* wq = (const float*)d_in[4];
  const float* wk = (const float*)d_in[5];
  const float* wv = (const float*)d_in[6];
  const float* wo = (const float*)d_in[7];
  float* out = (float*)d_out;

  unsigned short* xb   = (unsigned short*)d_ws;               // 4096 x 2048 (dead after gemm1)
  unsigned short* wqkv = xb + (size_t)4096 * 2048;            // 3072 x 2048
  unsigned short* wob  = wqkv + (size_t)3072 * 2048;          // 2048 x 2048
  unsigned short* qkv  = wob + (size_t)2048 * 2048;           // 4096 x 3072
  unsigned short* ob   = qkv + (size_t)4096 * 3072;           // 4096 x 2048
  unsigned short* vtb  = xb;                                  // 4*8*64*1024 (reuses xb)

  hipFuncSetAttribute((const void*)&gemm8p<false, 256, 12, 16>,
                      hipFuncAttributeMaxDynamicSharedMemorySize, 131072);
  hipFuncSetAttribute((const void*)&gemm8p<true, 128, 16, 16>,
                      hipFuncAttributeMaxDynamicSharedMemorySize, 98304);

  CvtArgs ca;
  ca.src[0] = input; ca.dst[0] = xb;                        ca.n[0] = (long)4096 * 2048;
  ca.src[1] = wq;    ca.dst[1] = wqkv;                      ca.n[1] = (long)2048 * 2048;
  ca.src[2] = wk;    ca.dst[2] = wqkv + (size_t)2048 * 2048; ca.n[2] = (long)512 * 2048;
  ca.src[3] = wv;    ca.dst[3] = wqkv + (size_t)2560 * 2048; ca.n[3] = (long)512 * 2048;
  ca.src[4] = wo;    ca.dst[4] = wob;                       ca.n[4] = (long)2048 * 2048;
  hipLaunchKernelGGL(cvt5_kernel, dim3(2048), dim3(256), 0, stream, ca);

  // fused QKV projection: qkv = xb @ wqkv^T  (M=4096, N=3072, K=2048)
  hipLaunchKernelGGL((gemm8p<false, 256, 12, 16>), dim3(12, 16), dim3(512), 131072,
                     stream, xb, wqkv, (void*)qkv, 3072);

  // K-RoPE in place + V transpose
  hipLaunchKernelGGL(ropekv_kernel, dim3(16, 8, 4), dim3(256), 0, stream,
                     qkv, fcos, fsin, vtb);

  // flash attention (Q-RoPE fused) -> ob (b,t,h,d) bf16
  hipLaunchKernelGGL(attn_kernel, dim3(16, 8, 4), dim3(256), 0, stream,
                     qkv, vtb, fcos, fsin, ob);

  // output projection: out = ob @ wob^T  (M=4096, N=2048, K=2048), fp32 out
  hipLaunchKernelGGL((gemm8p<true, 128, 16, 16>), dim3(16, 16), dim3(512), 98304,
                     stream, ob, wob, (void*)out, 2048);
}

// Round 11
// 163.933 us; speedup vs baseline: 1.0478x; 1.0264x over previous
//
#include <hip/hip_runtime.h>
#include <cstdint>

// ---- types ----
typedef __bf16 bf16x8 __attribute__((ext_vector_type(8)));
typedef float  f32x4  __attribute__((ext_vector_type(4)));
typedef float  f32x16 __attribute__((ext_vector_type(16)));
typedef float  float8v __attribute__((ext_vector_type(8)));
typedef unsigned short ushort8v __attribute__((ext_vector_type(8)));
typedef unsigned short ushort4v __attribute__((ext_vector_type(4)));
typedef unsigned int   uint4v   __attribute__((ext_vector_type(4)));

__device__ __forceinline__ unsigned short f2b(float f) {
  uint32_t u = __builtin_bit_cast(uint32_t, f);
  u += 0x7FFFu + ((u >> 16) & 1u);     // round-to-nearest-even
  return (unsigned short)(u >> 16);
}
__device__ __forceinline__ float b2f(unsigned short h) {
  uint32_t u = ((uint32_t)h) << 16;
  return __builtin_bit_cast(float, u);
}
__device__ __forceinline__ unsigned int cvtpk(float lo, float hi_) {
  unsigned int r;
  asm("v_cvt_pk_bf16_f32 %0, %1, %2" : "=v"(r) : "v"(lo), "v"(hi_));
  return r;
}

__device__ __forceinline__ void async16(const void* g, void* l) {
  __builtin_amdgcn_global_load_lds(
      (const __attribute__((address_space(1))) void*)g,
      (__attribute__((address_space(3))) void*)l, 16, 0, 0);
}

// s_waitcnt immediates (gfx9 encoding): vmcnt[3:0]|[15:14], expcnt[6:4], lgkmcnt[11:8]
#define WAITVM(N)  __builtin_amdgcn_s_waitcnt(0x0F70 | ((N) & 15))

// ---- fused fp32 -> bf16 convert, 5 segments in one launch ----
struct CvtArgs {
  const float* src[5];
  unsigned short* dst[5];
  long n[5];
};
__global__ void cvt5_kernel(CvtArgs a) {
  long base = (long)blockIdx.x * blockDim.x + threadIdx.x;
  long gstride = (long)gridDim.x * blockDim.x;
#pragma unroll 1
  for (int sg = 0; sg < 5; ++sg) {
    const float* s = a.src[sg];
    unsigned short* d = a.dst[sg];
    long n8 = a.n[sg] >> 3;
    for (long i = base; i < n8; i += gstride) {
      float8v f = *(const float8v*)(s + i * 8);
      ushort8v o;
#pragma unroll
      for (int j = 0; j < 8; ++j) o[j] = f2b(f[j]);
      *(ushort8v*)(d + i * 8) = o;
    }
  }
}

// ---- QKV GEMM, full-chip grid: BN=192, 16x16=256 blocks ----
// BM=256, BK=64, 8 waves (2m x 4n), NF=3 (wave tile 128x48). A: 4-slot k-half
// ring (16KB each, packed-frag layout). B: 2-slot full-BK ring (24KB each,
// row-major 128B rows, XOR-swizzled chunks; 3 gloads/thread uniform).
// Per tile stages {A1(T+1)@ph0, A0(T+2)@ph2, B(T+2)@ph3}; ONE counted
// vmcnt(5) per K-tile at ph3 (confirms exactly tile T+1; never 0 till tail).
// All slot overwrites land >=1 phase-end barrier after the slot's last read.
__global__ __launch_bounds__(512, 2)
void gemmQ192(const unsigned short* __restrict__ Ag, const unsigned short* __restrict__ Wg,
              unsigned short* __restrict__ Cp) {
  constexpr int K = 2048;
  constexpr int NF = 3;
  constexpr int ASLOT = 16384;        // 256 rows x 32k x 2B
  constexpr int BSLOT = 24576;        // 192 rows x 64k x 2B
  constexpr int N = 3072;

  extern __shared__ char lds_c[];

  const int tid = threadIdx.x;
  const int wave = tid >> 6, lane = tid & 63;
  const int wm = wave >> 2, wn = wave & 3;
  const int lr = lane & 15, lg = lane >> 4;

  // T1 chunked XCD swizzle, nwg=256, cpx=32
  const int flat = blockIdx.y * 16 + blockIdx.x;
  const int swz = (flat & 7) * 32 + (flat >> 3);
  const int m0 = (swz >> 4) * 256, n0 = (swz & 15) * 192;

  const int laneSw = (lr >> 1) * 128 + (((((lr & 1) << 2) | lg) ^ (lr >> 1)) << 4);
  const int aoff = wm * 8192 + laneSw;

  // B frag read precompute: row = wn*48 + ni*16 + lr
  int bByte[NF], bR7[NF];
#pragma unroll
  for (int ni = 0; ni < NF; ++ni) {
    int row = wn * 48 + ni * 16 + lr;
    bByte[ni] = row * 128;
    bR7[ni] = row & 7;
  }

  f32x4 acc[8][NF] = {};
  bf16x8 af[4], bf[NF];

  auto stA = [&](int slot, int s) {        // s = global k-half index
    char* sl = lds_c + slot * ASLOT;
    const int kc = s * 32;
#pragma unroll
    for (int j = 0; j < 2; ++j) {
      int q = (tid + 512 * j) * 16;
      int R = q >> 7, g2L = ((q >> 4) & 7) ^ (R & 7);
      int row = R * 2 + (g2L >> 2), kg = g2L & 3;
      async16(Ag + (size_t)(m0 + row) * K + kc + kg * 8, sl + q);
    }
  };
  auto stB = [&](int slot, int T) {        // full-BK unit for K-tile T
    char* sl = lds_c + 4 * ASLOT + slot * BSLOT;
    const int kc = T * 64;
#pragma unroll
    for (int j = 0; j < 3; ++j) {
      int q = (tid + 512 * j) * 16;
      int row = q >> 7, c = (q >> 4) & 7;
      async16(Wg + (size_t)(n0 + row) * K + kc + ((c ^ (row & 7)) * 8), sl + q);
    }
  };

#define PH(SA, SB, MH, KH, RDB, STG, VM)                                      \
  {                                                                           \
    const char* As_ = lds_c + (SA) * ASLOT;                                   \
    _Pragma("unroll") for (int mi = 0; mi < 4; ++mi)                          \
      af[mi] = *(const bf16x8*)(As_ + aoff + ((MH) * 4 + mi) * 1024);         \
    if (RDB) {                                                                \
      const char* Bs_ = lds_c + 4 * ASLOT + (SB) * BSLOT;                     \
      _Pragma("unroll") for (int ni = 0; ni < NF; ++ni)                       \
        bf[ni] = *(const bf16x8*)(Bs_ + bByte[ni] +                           \
                                  (((((KH) << 2) | lg) ^ bR7[ni]) << 4));     \
    }                                                                         \
    STG;                                                                      \
    if ((VM) >= 0) WAITVM(VM);                                                \
    __builtin_amdgcn_s_barrier();                                             \
    __builtin_amdgcn_s_setprio(1);                                            \
    _Pragma("unroll") for (int mi = 0; mi < 4; ++mi)                          \
      _Pragma("unroll") for (int ni = 0; ni < NF; ++ni)                       \
        acc[(MH) * 4 + mi][ni] = __builtin_amdgcn_mfma_f32_16x16x32_bf16(     \
            af[mi], bf[ni], acc[(MH) * 4 + mi][ni], 0, 0, 0);                 \
    __builtin_amdgcn_s_setprio(0);                                            \
    __builtin_amdgcn_s_barrier();                                             \
  }

  // prologue (oldest->youngest): B(0)[3] A0(0)[2] A1(0)[2] B(1)[3] A0(1)[2]
  stB(0, 0); stA(0, 0); stA(1, 1); stB(1, 1); stA(2, 2);
  WAITVM(5);            // confirms B(0),A0(0),A1(0); leaves {B(1),A0(1)}=5
  __builtin_amdgcn_s_barrier();

  for (int t2 = 0; t2 < 30; t2 += 2) {
    // even tile T=t2: A slots {0,1}, B slot 0
    PH(0, 0, 0, 0, true,  stA(3, 2 * t2 + 3), -1);   // stage A1(T+1)
    PH(0, 0, 1, 0, false, (void)0, -1);
    PH(1, 0, 0, 1, true,  stA(0, 2 * t2 + 4), -1);   // stage A0(T+2)
    PH(1, 0, 1, 1, false, stB(0, t2 + 2), 5);        // stage B(T+2); confirm T+1
    // odd tile T=t2+1: A slots {2,3}, B slot 1
    PH(2, 1, 0, 0, true,  stA(1, 2 * t2 + 5), -1);
    PH(2, 1, 1, 0, false, (void)0, -1);
    PH(3, 1, 0, 1, true,  stA(2, 2 * t2 + 6), -1);
    PH(3, 1, 1, 1, false, stB(1, t2 + 3), 5);
  }
  // tile 30: stage A1(31) then drain
  PH(0, 0, 0, 0, true,  stA(3, 63), -1);
  PH(0, 0, 1, 0, false, (void)0, -1);
  PH(1, 0, 0, 1, true,  (void)0, -1);
  PH(1, 0, 1, 1, false, (void)0, 0);
  // tile 31: pure compute
  PH(2, 1, 0, 0, true,  (void)0, -1);
  PH(2, 1, 1, 0, false, (void)0, -1);
  PH(3, 1, 0, 1, true,  (void)0, -1);
  PH(3, 1, 1, 1, false, (void)0, -1);
#undef PH

  // epilogue: C/D layout col=lane&15, row=(lane>>4)*4+j
#pragma unroll
  for (int mig = 0; mig < 8; ++mig) {
#pragma unroll
    for (int j = 0; j < 4; ++j) {
      int row = m0 + wm * 128 + mig * 16 + lg * 4 + j;
#pragma unroll
      for (int ni = 0; ni < NF; ++ni) {
        int col = n0 + wn * 48 + ni * 16 + lr;
        Cp[(size_t)row * N + col] = f2b(acc[mig][ni][j]);
      }
    }
  }
}

// ---- 8-phase GEMM (r10 structure) — used for the WO projection ----
template<bool F32OUT, int BN, int GX, int GY>
__global__ __launch_bounds__(512, 2)
void gemm8p(const unsigned short* __restrict__ Ag, const unsigned short* __restrict__ Wg,
            void* __restrict__ Cp, int N) {
  constexpr int K = 2048;
  constexpr int BM = 256;
  constexpr int NF = BN / 64;
  constexpr int AL = 2;
  constexpr int BL = BN / 128;
  constexpr int VMS = 2 * BL + AL;
  constexpr int ASLOT = BM * 64;
  constexpr int BSLOT = BN * 64;
  constexpr int NWG = GX * GY;
  constexpr int CPX = NWG / 8;

  extern __shared__ char lds_c[];

  const int tid = threadIdx.x;
  const int wave = tid >> 6, lane = tid & 63;
  const int wm = wave >> 2, wn = wave & 3;
  const int lr = lane & 15, lg = lane >> 4;

  const int flat = blockIdx.y * GX + blockIdx.x;
  const int swz = (flat & 7) * CPX + (flat >> 3);
  const int m0 = (swz / GX) * BM, n0 = (swz % GX) * BN;

  const int laneSw = (lr >> 1) * 128 + (((((lr & 1) << 2) | lg) ^ (lr >> 1)) << 4);
  const int aoff = wm * 128 * 64 + laneSw;
  const int boff = wn * NF * 1024 + laneSw;

  f32x4 acc[8][NF] = {};
  bf16x8 af[4], bf[NF];

  auto stA = [&](int slot, int s) {
    char* sl = lds_c + slot * ASLOT;
    const int kc = s * 32;
#pragma unroll
    for (int j = 0; j < AL; ++j) {
      int q = (tid + 512 * j) * 16;
      int R = q >> 7, g2L = ((q >> 4) & 7) ^ (R & 7);
      int row = R * 2 + (g2L >> 2), kg = g2L & 3;
      async16(Ag + (size_t)(m0 + row) * K + kc + kg * 8, sl + q);
    }
  };
  auto stB = [&](int slot, int s) {
    char* sl = lds_c + 4 * ASLOT + slot * BSLOT;
    const int kc = s * 32;
#pragma unroll
    for (int j = 0; j < BL; ++j) {
      int q = (tid + 512 * j) * 16;
      int R = q >> 7, g2L = ((q >> 4) & 7) ^ (R & 7);
      int row = R * 2 + (g2L >> 2), kg = g2L & 3;
      async16(Wg + (size_t)(n0 + row) * K + kc + kg * 8, sl + q);
    }
  };

#define PH(RSLOT, MH, RDB, STG, VM)                                           \
  {                                                                           \
    const char* As_ = lds_c + (RSLOT) * ASLOT;                                \
    _Pragma("unroll") for (int mi = 0; mi < 4; ++mi)                          \
      af[mi] = *(const bf16x8*)(As_ + aoff + ((MH) * 4 + mi) * 1024);         \
    if (RDB) {                                                                \
      const char* Bs_ = lds_c + 4 * ASLOT + (RSLOT) * BSLOT;                  \
      _Pragma("unroll") for (int ni = 0; ni < NF; ++ni)                       \
        bf[ni] = *(const bf16x8*)(Bs_ + boff + ni * 1024);                    \
    }                                                                         \
    STG;                                                                      \
    if ((VM) >= 0) WAITVM(VM);                                                \
    __builtin_amdgcn_s_barrier();                                             \
    __builtin_amdgcn_s_setprio(1);                                            \
    _Pragma("unroll") for (int mi = 0; mi < 4; ++mi)                          \
      _Pragma("unroll") for (int ni = 0; ni < NF; ++ni)                       \
        acc[(MH) * 4 + mi][ni] = __builtin_amdgcn_mfma_f32_16x16x32_bf16(     \
            af[mi], bf[ni], acc[(MH) * 4 + mi][ni], 0, 0, 0);                 \
    __builtin_amdgcn_s_setprio(0);                                            \
    __builtin_amdgcn_s_barrier();                                             \
  }

  stB(0, 0); stA(0, 0); stB(1, 1); stA(1, 1); stB(2, 2); stA(2, 2); stB(3, 3);
  WAITVM(VMS);
  __builtin_amdgcn_s_barrier();

  for (int T = 0; T < 30; T += 2) {
    const int p0 = 2 * T;
    PH(0, 0, true,  stA(3, p0 + 3), -1);
    PH(0, 1, false, stB(0, p0 + 4), -1);
    PH(1, 0, true,  stA(0, p0 + 4), -1);
    PH(1, 1, false, stB(1, p0 + 5), VMS);
    PH(2, 0, true,  stA(1, p0 + 5), -1);
    PH(2, 1, false, stB(2, p0 + 6), -1);
    PH(3, 0, true,  stA(2, p0 + 6), -1);
    PH(3, 1, false, stB(3, p0 + 7), VMS);
  }
  PH(0, 0, true,  stA(3, 63), -1);
  PH(0, 1, false, (void)0, -1);
  PH(1, 0, true,  (void)0, -1);
  PH(1, 1, false, (void)0, 0);
  PH(2, 0, true,  (void)0, -1);
  PH(2, 1, false, (void)0, -1);
  PH(3, 0, true,  (void)0, -1);
  PH(3, 1, false, (void)0, -1);
#undef PH

#pragma unroll
  for (int mig = 0; mig < 8; ++mig) {
#pragma unroll
    for (int j = 0; j < 4; ++j) {
      int row = m0 + wm * 128 + mig * 16 + lg * 4 + j;
#pragma unroll
      for (int ni = 0; ni < NF; ++ni) {
        int col = n0 + wn * (NF * 16) + ni * 16 + lr;
        float v = acc[mig][ni][j];
        if (F32OUT) ((float*)Cp)[(size_t)row * N + col] = v;
        else        ((unsigned short*)Cp)[(size_t)row * N + col] = f2b(v);
      }
    }
  }
}

// ---- fused K-RoPE (in place) + V transpose -> vt[b][kvh][d=64][t=1024] ----
__global__ __launch_bounds__(256)
void ropekv_kernel(unsigned short* __restrict__ qkv,
                   const float* __restrict__ cosb, const float* __restrict__ sinb,
                   unsigned short* __restrict__ vt) {
  const int tt0 = blockIdx.x * 64;
  const int kvh = blockIdx.y;
  const int b   = blockIdx.z;
  const int tid = threadIdx.x;

  {
    int r = tid >> 2, c0 = (tid & 3) * 16;
    int t = tt0 + r;
    unsigned short* kp = qkv + (size_t)(b * 1024 + t) * 3072 + 2048 + kvh * 64 + c0;
    const float* cb = cosb + t * 32 + c0 / 2;
    const float* sb = sinb + t * 32 + c0 / 2;
    ushort8v x0 = *(const ushort8v*)kp;
    ushort8v x1 = *(const ushort8v*)(kp + 8);
    float8v c = *(const float8v*)cb;
    float8v s = *(const float8v*)sb;
    ushort8v o0, o1;
#pragma unroll
    for (int j = 0; j < 4; ++j) {
      float xr = b2f(x0[2 * j]), xi = b2f(x0[2 * j + 1]);
      o0[2 * j]     = f2b(xr * c[j] - xi * s[j]);
      o0[2 * j + 1] = f2b(xr * s[j] + xi * c[j]);
    }
#pragma unroll
    for (int j = 0; j < 4; ++j) {
      float xr = b2f(x1[2 * j]), xi = b2f(x1[2 * j + 1]);
      o1[2 * j]     = f2b(xr * c[4 + j] - xi * s[4 + j]);
      o1[2 * j + 1] = f2b(xr * s[4 + j] + xi * c[4 + j]);
    }
    *(ushort8v*)kp = o0;
    *(ushort8v*)(kp + 8) = o1;
  }

  __shared__ unsigned short lT[64 * 68];
#pragma unroll
  for (int i = 0; i < 2; ++i) {
    int r = i * 32 + (tid >> 3), c = (tid & 7) * 8;
    const unsigned short* src = qkv + (size_t)(b * 1024 + tt0 + r) * 3072 + 2560 + kvh * 64 + c;
    ushort8v v = *(const ushort8v*)src;
    ushort4v a, b4;
#pragma unroll
    for (int j = 0; j < 4; ++j) { a[j] = v[j]; b4[j] = v[j + 4]; }
    *(ushort4v*)&lT[r * 68 + c]     = a;
    *(ushort4v*)&lT[r * 68 + c + 4] = b4;
  }
  __syncthreads();
#pragma unroll
  for (int i = 0; i < 2; ++i) {
    int d = tid & 63;
    int tt = i * 4 + (tid >> 6);
    ushort8v o;
#pragma unroll
    for (int j = 0; j < 8; ++j) o[j] = lT[(tt * 8 + j) * 68 + d];
    *(ushort8v*)&vt[((size_t)((b * 8 + kvh) * 64 + d)) * 1024 + tt0 + tt * 8] = o;
  }
}

// ---- flash attention: paired q-tiles processed SEQUENTIALLY (one live state) ----
__global__ __launch_bounds__(256, 2)
void attn_kernel(const unsigned short* __restrict__ qkv, const unsigned short* __restrict__ vt,
                 const float* __restrict__ cosb, const float* __restrict__ sinb,
                 unsigned short* __restrict__ ob) {
  const int flat = (blockIdx.z * 8 + blockIdx.y) * 16 + blockIdx.x;
  const int swzb = (flat & 7) * 64 + (flat >> 3);
  const int bx = swzb & 15, kvh = (swzb >> 4) & 7, b = swzb >> 7;

  const int tid = threadIdx.x, wave = tid >> 6, lane = tid & 63;
  const int l31 = lane & 31, hi = lane >> 5;
  const int h = kvh * 4 + wave;

  const int qth = 31 - bx, qtl = bx;
  const int q0h = qth * 32, q0l = qtl * 32;
  const int nth = qth / 4 + 1, ntl = qtl / 4 + 1;
  const int ntot = nth + ntl;

  __shared__ unsigned short lK[2][128 * 64];
  __shared__ unsigned short lVt[2][64 * 128];

  auto ldq = [&](int q0, bf16x8* qf) {
    int t = q0 + l31;
    const unsigned short* qp = qkv + (size_t)(b * 1024 + t) * 3072 + h * 64;
#pragma unroll
    for (int dk = 0; dk < 4; ++dk) {
      ushort8v q = *(const ushort8v*)(qp + dk * 16 + hi * 8);
      f32x4 c4 = *(const f32x4*)(cosb + t * 32 + dk * 8 + hi * 4);
      f32x4 s4 = *(const f32x4*)(sinb + t * 32 + dk * 8 + hi * 4);
      ushort8v o;
#pragma unroll
      for (int j = 0; j < 4; ++j) {
        float xr = b2f(q[2 * j]), xi = b2f(q[2 * j + 1]);
        o[2 * j]     = f2b(xr * c4[j] - xi * s4[j]);
        o[2 * j + 1] = f2b(xr * s4[j] + xi * c4[j]);
      }
      qf[dk] = __builtin_bit_cast(bf16x8, o);
    }
  };

  const unsigned short* kg = qkv + (size_t)(b * 1024) * 3072 + 2048 + kvh * 64;
  const unsigned short* vg = vt + (size_t)(b * 8 + kvh) * 64 * 1024;

  auto stage = [&](int kvb, int bi) {
    const int sr  = tid >> 3;
    const int scb = (tid & 7) * 16;
#pragma unroll
    for (int i = 0; i < 4; ++i) {
      int r = i * 32 + sr;
      int cb = scb ^ ((r & 7) << 4);
      async16(kg + (size_t)(kvb + r) * 3072 + (cb >> 1), &lK[bi][r * 64 + (scb >> 1)]);
    }
    const int rv0 = tid >> 4;
    const int scv = (tid & 15) * 16;
#pragma unroll
    for (int i = 0; i < 4; ++i) {
      int rv = i * 16 + rv0;
      int cbv = scv ^ ((rv & 15) << 4);
      async16(vg + (size_t)rv * 1024 + kvb + (cbv >> 1), &lVt[bi][rv * 128 + (scv >> 1)]);
    }
  };

  bf16x8 qf[4];
  f32x16 oacc[2] = {};
  float m2 = -3e38f, l_run = 0.f;
  int q0 = q0h;

  ldq(q0h, qf);

  const float SC = 0.125f * 1.44269504f;

  auto chunk64 = [&](int cur, int ckvb, int c, bool lastT) {
    f32x16 sd[2] = {};
    __builtin_amdgcn_s_setprio(1);
#pragma unroll
    for (int s = 0; s < 2; ++s) {
      const int krow = c * 64 + s * 32 + l31;
      const char* kr = (const char*)lK[cur] + krow * 128;
      const int swz = (krow & 7) << 4;
#pragma unroll
      for (int dk = 0; dk < 4; ++dk) {
        bf16x8 kf = *(const bf16x8*)(kr + ((dk * 32 + hi * 16) ^ swz));
        sd[s] = __builtin_amdgcn_mfma_f32_32x32x16_bf16(kf, qf[dk], sd[s], 0, 0, 0);
      }
    }
    __builtin_amdgcn_s_setprio(0);

#pragma unroll
    for (int s = 0; s < 2; ++s)
#pragma unroll
      for (int r = 0; r < 16; ++r) {
        float v = sd[s][r] * SC;
        if (lastT) {
          int kvg = ckvb + s * 32 + (r & 3) + 8 * (r >> 2) + 4 * hi;
          if (kvg > q0 + l31) v = -3e38f;
        }
        sd[s][r] = v;
      }
    float pm = sd[0][0];
#pragma unroll
    for (int s = 0; s < 2; ++s)
#pragma unroll
      for (int r = 0; r < 16; ++r) pm = fmaxf(pm, sd[s][r]);
    pm = fmaxf(pm, __shfl_xor(pm, 32));
    if (!__all(pm <= m2 + 11.0f)) {          // T13 defer-max (log2 domain)
      float mnew = fmaxf(m2, pm);
      float alpha = exp2f(m2 - mnew);
      m2 = mnew;
      l_run *= alpha;
#pragma unroll
      for (int db = 0; db < 2; ++db)
#pragma unroll
        for (int r = 0; r < 16; ++r) oacc[db][r] *= alpha;
    }
    float tsum = 0.f;
#pragma unroll
    for (int s = 0; s < 2; ++s)
#pragma unroll
      for (int r = 0; r < 16; ++r) { float p = exp2f(sd[s][r] - m2); sd[s][r] = p; tsum += p; }
    tsum += __shfl_xor(tsum, 32);
    l_run += tsum;

    bf16x8 pf[2][2];
#pragma unroll
    for (int s = 0; s < 2; ++s)
#pragma unroll
      for (int kc = 0; kc < 2; ++kc) {
        unsigned int cA = cvtpk(sd[s][8 * kc + 0], sd[s][8 * kc + 1]);
        unsigned int cB = cvtpk(sd[s][8 * kc + 4], sd[s][8 * kc + 5]);
        unsigned int cC = cvtpk(sd[s][8 * kc + 2], sd[s][8 * kc + 3]);
        unsigned int cD = cvtpk(sd[s][8 * kc + 6], sd[s][8 * kc + 7]);
        unsigned int xA = __shfl_xor(cA, 32), xB = __shfl_xor(cB, 32);
        unsigned int xC = __shfl_xor(cC, 32), xD = __shfl_xor(cD, 32);
        uint4v u;
        u[0] = hi ? xB : cA;
        u[1] = hi ? xD : cC;
        u[2] = hi ? cB : xA;
        u[3] = hi ? cD : xC;
        pf[s][kc] = __builtin_bit_cast(bf16x8, u);
      }

    __builtin_amdgcn_s_setprio(1);
#pragma unroll
    for (int db = 0; db < 2; ++db) {
      const int row = db * 32 + l31;
      const char* vr = (const char*)lVt[cur] + row * 256;
      const int vswz = (row & 15) << 4;
#pragma unroll
      for (int s = 0; s < 2; ++s)
#pragma unroll
        for (int kc = 0; kc < 2; ++kc) {
          bf16x8 vf = *(const bf16x8*)(vr + ((c * 128 + s * 64 + kc * 32 + hi * 16) ^ vswz));
          oacc[db] = __builtin_amdgcn_mfma_f32_32x32x16_bf16(vf, pf[s][kc], oacc[db], 0, 0, 0);
        }
    }
    __builtin_amdgcn_s_setprio(0);
  };

  auto writeOut = [&](int q0w) {
    float inv = 1.0f / l_run;
    unsigned short* orow = ob + (size_t)(b * 1024 + q0w + l31) * 2048 + h * 64;
#pragma unroll
    for (int db = 0; db < 2; ++db)
#pragma unroll
      for (int g = 0; g < 4; ++g) {
        int d0 = db * 32 + 8 * g + 4 * hi;
        ushort4v o;
#pragma unroll
        for (int j = 0; j < 4; ++j) o[j] = f2b(oacc[db][4 * g + j] * inv);
        *(ushort4v*)(orow + d0) = o;
      }
  };

  auto kvb_of = [&](int j) { return (j < nth ? j : j - nth) * 128; };

  stage(0, 0);
  __syncthreads();

  for (int j = 0; j < ntot; ++j) {
    const int cur = j & 1;
    if (j + 1 < ntot) stage(kvb_of(j + 1), cur ^ 1);   // issue-early (T14)
    const int kvb = kvb_of(j);
    const bool lastT = (j == nth - 1) || (j == ntot - 1);

#pragma unroll 1
    for (int c = 0; c < 2; ++c) {
      if (kvb + c * 64 > q0 + 31) continue;   // fully-masked chunk (uniform)
      chunk64(cur, kvb + c * 64, c, lastT);
    }

    if (j == nth - 1) {                        // hi pass done -> switch to lo
      writeOut(q0h);
      oacc[0] = f32x16{}; oacc[1] = f32x16{};
      m2 = -3e38f; l_run = 0.f;
      q0 = q0l;
      ldq(q0l, qf);
    }
    __syncthreads();   // drains prefetch + buffer handoff
  }
  writeOut(q0l);
}

extern "C" void kernel_launch(void* const* d_in, const int* in_sizes, int n_in,
                              void* d_out, int out_size, void* d_ws, size_t ws_size,
                              hipStream_t stream) {
  const float* input = (const float*)d_in[0];
  const float* fcos  = (const float*)d_in[1];
  const float* fsin  = (const float*)d_in[2];
  const float* wq = (const float*)d_in[4];
  const float* wk = (const float*)d_in[5];
  const float* wv = (const float*)d_in[6];
  const float* wo = (const float*)d_in[7];
  float* out = (float*)d_out;

  unsigned short* xb   = (unsigned short*)d_ws;               // 4096 x 2048 (dead after gemm1)
  unsigned short* wqkv = xb + (size_t)4096 * 2048;            // 3072 x 2048
  unsigned short* wob  = wqkv + (size_t)3072 * 2048;          // 2048 x 2048
  unsigned short* qkv  = wob + (size_t)2048 * 2048;           // 4096 x 3072
  unsigned short* ob   = qkv + (size_t)4096 * 3072;           // 4096 x 2048
  unsigned short* vtb  = xb;                                  // 4*8*64*1024 (reuses xb)

  hipFuncSetAttribute((const void*)&gemmQ192,
                      hipFuncAttributeMaxDynamicSharedMemorySize, 114688);
  hipFuncSetAttribute((const void*)&gemm8p<true, 128, 16, 16>,
                      hipFuncAttributeMaxDynamicSharedMemorySize, 98304);

  CvtArgs ca;
  ca.src[0] = input; ca.dst[0] = xb;                        ca.n[0] = (long)4096 * 2048;
  ca.src[1] = wq;    ca.dst[1] = wqkv;                      ca.n[1] = (long)2048 * 2048;
  ca.src[2] = wk;    ca.dst[2] = wqkv + (size_t)2048 * 2048; ca.n[2] = (long)512 * 2048;
  ca.src[3] = wv;    ca.dst[3] = wqkv + (size_t)2560 * 2048; ca.n[3] = (long)512 * 2048;
  ca.src[4] = wo;    ca.dst[4] = wob;                       ca.n[4] = (long)2048 * 2048;
  hipLaunchKernelGGL(cvt5_kernel, dim3(2048), dim3(256), 0, stream, ca);

  // fused QKV projection: qkv = xb @ wqkv^T  (M=4096, N=3072, K=2048), full-chip grid
  hipLaunchKernelGGL(gemmQ192, dim3(16, 16), dim3(512), 114688,
                     stream, xb, wqkv, qkv);

  // K-RoPE in place + V transpose
  hipLaunchKernelGGL(ropekv_kernel, dim3(16, 8, 4), dim3(256), 0, stream,
                     qkv, fcos, fsin, vtb);

  // flash attention (Q-RoPE fused) -> ob (b,t,h,d) bf16
  hipLaunchKernelGGL(attn_kernel, dim3(16, 8, 4), dim3(256), 0, stream,
                     qkv, vtb, fcos, fsin, ob);

  // output projection: out = ob @ wob^T  (M=4096, N=2048, K=2048), fp32 out
  hipLaunchKernelGGL((gemm8p<true, 128, 16, 16>), dim3(16, 16), dim3(512), 98304,
                     stream, ob, wob, (void*)out, 2048);
}

// Round 12
// 163.546 us; speedup vs baseline: 1.0503x; 1.0024x over previous
//
#include <hip/hip_runtime.h>
#include <cstdint>

// ---- types ----
typedef __bf16 bf16x8 __attribute__((ext_vector_type(8)));
typedef float  f32x4  __attribute__((ext_vector_type(4)));
typedef float  f32x16 __attribute__((ext_vector_type(16)));
typedef float  float8v __attribute__((ext_vector_type(8)));
typedef unsigned short ushort8v __attribute__((ext_vector_type(8)));
typedef unsigned short ushort4v __attribute__((ext_vector_type(4)));
typedef unsigned int   uint4v   __attribute__((ext_vector_type(4)));

__device__ __forceinline__ unsigned short f2b(float f) {
  uint32_t u = __builtin_bit_cast(uint32_t, f);
  u += 0x7FFFu + ((u >> 16) & 1u);     // round-to-nearest-even
  return (unsigned short)(u >> 16);
}
__device__ __forceinline__ float b2f(unsigned short h) {
  uint32_t u = ((uint32_t)h) << 16;
  return __builtin_bit_cast(float, u);
}
__device__ __forceinline__ unsigned int cvtpk(float lo, float hi_) {
  unsigned int r;
  asm("v_cvt_pk_bf16_f32 %0, %1, %2" : "=v"(r) : "v"(lo), "v"(hi_));
  return r;
}

__device__ __forceinline__ void async16(const void* g, void* l) {
  __builtin_amdgcn_global_load_lds(
      (const __attribute__((address_space(1))) void*)g,
      (__attribute__((address_space(3))) void*)l, 16, 0, 0);
}

// s_waitcnt immediates (gfx9 encoding): vmcnt[3:0]|[15:14], expcnt[6:4], lgkmcnt[11:8]
#define WAITVM(N)  __builtin_amdgcn_s_waitcnt(0x0F70 | ((N) & 15))

// ---- fused fp32 -> bf16 convert, 5 segments in one launch ----
struct CvtArgs {
  const float* src[5];
  unsigned short* dst[5];
  long n[5];
};
__global__ void cvt5_kernel(CvtArgs a) {
  long base = (long)blockIdx.x * blockDim.x + threadIdx.x;
  long gstride = (long)gridDim.x * blockDim.x;
#pragma unroll 1
  for (int sg = 0; sg < 5; ++sg) {
    const float* s = a.src[sg];
    unsigned short* d = a.dst[sg];
    long n8 = a.n[sg] >> 3;
    for (long i = base; i < n8; i += gstride) {
      float8v f = *(const float8v*)(s + i * 8);
      ushort8v o;
#pragma unroll
      for (int j = 0; j < 8; ++j) o[j] = f2b(f[j]);
      *(ushort8v*)(d + i * 8) = o;
    }
  }
}

// ---- QKV GEMM, full-chip grid: BN=192, 16x16=256 blocks (r11, unchanged) ----
__global__ __launch_bounds__(512, 2)
void gemmQ192(const unsigned short* __restrict__ Ag, const unsigned short* __restrict__ Wg,
              unsigned short* __restrict__ Cp) {
  constexpr int K = 2048;
  constexpr int NF = 3;
  constexpr int ASLOT = 16384;
  constexpr int BSLOT = 24576;
  constexpr int N = 3072;

  extern __shared__ char lds_c[];

  const int tid = threadIdx.x;
  const int wave = tid >> 6, lane = tid & 63;
  const int wm = wave >> 2, wn = wave & 3;
  const int lr = lane & 15, lg = lane >> 4;

  const int flat = blockIdx.y * 16 + blockIdx.x;
  const int swz = (flat & 7) * 32 + (flat >> 3);
  const int m0 = (swz >> 4) * 256, n0 = (swz & 15) * 192;

  const int laneSw = (lr >> 1) * 128 + (((((lr & 1) << 2) | lg) ^ (lr >> 1)) << 4);
  const int aoff = wm * 8192 + laneSw;

  int bByte[NF], bR7[NF];
#pragma unroll
  for (int ni = 0; ni < NF; ++ni) {
    int row = wn * 48 + ni * 16 + lr;
    bByte[ni] = row * 128;
    bR7[ni] = row & 7;
  }

  f32x4 acc[8][NF] = {};
  bf16x8 af[4], bf[NF];

  auto stA = [&](int slot, int s) {
    char* sl = lds_c + slot * ASLOT;
    const int kc = s * 32;
#pragma unroll
    for (int j = 0; j < 2; ++j) {
      int q = (tid + 512 * j) * 16;
      int R = q >> 7, g2L = ((q >> 4) & 7) ^ (R & 7);
      int row = R * 2 + (g2L >> 2), kg = g2L & 3;
      async16(Ag + (size_t)(m0 + row) * K + kc + kg * 8, sl + q);
    }
  };
  auto stB = [&](int slot, int T) {
    char* sl = lds_c + 4 * ASLOT + slot * BSLOT;
    const int kc = T * 64;
#pragma unroll
    for (int j = 0; j < 3; ++j) {
      int q = (tid + 512 * j) * 16;
      int row = q >> 7, c = (q >> 4) & 7;
      async16(Wg + (size_t)(n0 + row) * K + kc + ((c ^ (row & 7)) * 8), sl + q);
    }
  };

#define PH(SA, SB, MH, KH, RDB, STG, VM)                                      \
  {                                                                           \
    const char* As_ = lds_c + (SA) * ASLOT;                                   \
    _Pragma("unroll") for (int mi = 0; mi < 4; ++mi)                          \
      af[mi] = *(const bf16x8*)(As_ + aoff + ((MH) * 4 + mi) * 1024);         \
    if (RDB) {                                                                \
      const char* Bs_ = lds_c + 4 * ASLOT + (SB) * BSLOT;                     \
      _Pragma("unroll") for (int ni = 0; ni < NF; ++ni)                       \
        bf[ni] = *(const bf16x8*)(Bs_ + bByte[ni] +                           \
                                  (((((KH) << 2) | lg) ^ bR7[ni]) << 4));     \
    }                                                                         \
    STG;                                                                      \
    if ((VM) >= 0) WAITVM(VM);                                                \
    __builtin_amdgcn_s_barrier();                                             \
    __builtin_amdgcn_s_setprio(1);                                            \
    _Pragma("unroll") for (int mi = 0; mi < 4; ++mi)                          \
      _Pragma("unroll") for (int ni = 0; ni < NF; ++ni)                       \
        acc[(MH) * 4 + mi][ni] = __builtin_amdgcn_mfma_f32_16x16x32_bf16(     \
            af[mi], bf[ni], acc[(MH) * 4 + mi][ni], 0, 0, 0);                 \
    __builtin_amdgcn_s_setprio(0);                                            \
    __builtin_amdgcn_s_barrier();                                             \
  }

  stB(0, 0); stA(0, 0); stA(1, 1); stB(1, 1); stA(2, 2);
  WAITVM(5);
  __builtin_amdgcn_s_barrier();

  for (int t2 = 0; t2 < 30; t2 += 2) {
    PH(0, 0, 0, 0, true,  stA(3, 2 * t2 + 3), -1);
    PH(0, 0, 1, 0, false, (void)0, -1);
    PH(1, 0, 0, 1, true,  stA(0, 2 * t2 + 4), -1);
    PH(1, 0, 1, 1, false, stB(0, t2 + 2), 5);
    PH(2, 1, 0, 0, true,  stA(1, 2 * t2 + 5), -1);
    PH(2, 1, 1, 0, false, (void)0, -1);
    PH(3, 1, 0, 1, true,  stA(2, 2 * t2 + 6), -1);
    PH(3, 1, 1, 1, false, stB(1, t2 + 3), 5);
  }
  PH(0, 0, 0, 0, true,  stA(3, 63), -1);
  PH(0, 0, 1, 0, false, (void)0, -1);
  PH(1, 0, 0, 1, true,  (void)0, -1);
  PH(1, 0, 1, 1, false, (void)0, 0);
  PH(2, 1, 0, 0, true,  (void)0, -1);
  PH(2, 1, 1, 0, false, (void)0, -1);
  PH(3, 1, 0, 1, true,  (void)0, -1);
  PH(3, 1, 1, 1, false, (void)0, -1);
#undef PH

#pragma unroll
  for (int mig = 0; mig < 8; ++mig) {
#pragma unroll
    for (int j = 0; j < 4; ++j) {
      int row = m0 + wm * 128 + mig * 16 + lg * 4 + j;
#pragma unroll
      for (int ni = 0; ni < NF; ++ni) {
        int col = n0 + wn * 48 + ni * 16 + lr;
        Cp[(size_t)row * N + col] = f2b(acc[mig][ni][j]);
      }
    }
  }
}

// ---- 8-phase GEMM (r10 structure) — used for the WO projection ----
template<bool F32OUT, int BN, int GX, int GY>
__global__ __launch_bounds__(512, 2)
void gemm8p(const unsigned short* __restrict__ Ag, const unsigned short* __restrict__ Wg,
            void* __restrict__ Cp, int N) {
  constexpr int K = 2048;
  constexpr int BM = 256;
  constexpr int NF = BN / 64;
  constexpr int AL = 2;
  constexpr int BL = BN / 128;
  constexpr int VMS = 2 * BL + AL;
  constexpr int ASLOT = BM * 64;
  constexpr int BSLOT = BN * 64;
  constexpr int NWG = GX * GY;
  constexpr int CPX = NWG / 8;

  extern __shared__ char lds_c[];

  const int tid = threadIdx.x;
  const int wave = tid >> 6, lane = tid & 63;
  const int wm = wave >> 2, wn = wave & 3;
  const int lr = lane & 15, lg = lane >> 4;

  const int flat = blockIdx.y * GX + blockIdx.x;
  const int swz = (flat & 7) * CPX + (flat >> 3);
  const int m0 = (swz / GX) * BM, n0 = (swz % GX) * BN;

  const int laneSw = (lr >> 1) * 128 + (((((lr & 1) << 2) | lg) ^ (lr >> 1)) << 4);
  const int aoff = wm * 128 * 64 + laneSw;
  const int boff = wn * NF * 1024 + laneSw;

  f32x4 acc[8][NF] = {};
  bf16x8 af[4], bf[NF];

  auto stA = [&](int slot, int s) {
    char* sl = lds_c + slot * ASLOT;
    const int kc = s * 32;
#pragma unroll
    for (int j = 0; j < AL; ++j) {
      int q = (tid + 512 * j) * 16;
      int R = q >> 7, g2L = ((q >> 4) & 7) ^ (R & 7);
      int row = R * 2 + (g2L >> 2), kg = g2L & 3;
      async16(Ag + (size_t)(m0 + row) * K + kc + kg * 8, sl + q);
    }
  };
  auto stB = [&](int slot, int s) {
    char* sl = lds_c + 4 * ASLOT + slot * BSLOT;
    const int kc = s * 32;
#pragma unroll
    for (int j = 0; j < BL; ++j) {
      int q = (tid + 512 * j) * 16;
      int R = q >> 7, g2L = ((q >> 4) & 7) ^ (R & 7);
      int row = R * 2 + (g2L >> 2), kg = g2L & 3;
      async16(Wg + (size_t)(n0 + row) * K + kc + kg * 8, sl + q);
    }
  };

#define PH(RSLOT, MH, RDB, STG, VM)                                           \
  {                                                                           \
    const char* As_ = lds_c + (RSLOT) * ASLOT;                                \
    _Pragma("unroll") for (int mi = 0; mi < 4; ++mi)                          \
      af[mi] = *(const bf16x8*)(As_ + aoff + ((MH) * 4 + mi) * 1024);         \
    if (RDB) {                                                                \
      const char* Bs_ = lds_c + 4 * ASLOT + (RSLOT) * BSLOT;                  \
      _Pragma("unroll") for (int ni = 0; ni < NF; ++ni)                       \
        bf[ni] = *(const bf16x8*)(Bs_ + boff + ni * 1024);                    \
    }                                                                         \
    STG;                                                                      \
    if ((VM) >= 0) WAITVM(VM);                                                \
    __builtin_amdgcn_s_barrier();                                             \
    __builtin_amdgcn_s_setprio(1);                                            \
    _Pragma("unroll") for (int mi = 0; mi < 4; ++mi)                          \
      _Pragma("unroll") for (int ni = 0; ni < NF; ++ni)                       \
        acc[(MH) * 4 + mi][ni] = __builtin_amdgcn_mfma_f32_16x16x32_bf16(     \
            af[mi], bf[ni], acc[(MH) * 4 + mi][ni], 0, 0, 0);                 \
    __builtin_amdgcn_s_setprio(0);                                            \
    __builtin_amdgcn_s_barrier();                                             \
  }

  stB(0, 0); stA(0, 0); stB(1, 1); stA(1, 1); stB(2, 2); stA(2, 2); stB(3, 3);
  WAITVM(VMS);
  __builtin_amdgcn_s_barrier();

  for (int T = 0; T < 30; T += 2) {
    const int p0 = 2 * T;
    PH(0, 0, true,  stA(3, p0 + 3), -1);
    PH(0, 1, false, stB(0, p0 + 4), -1);
    PH(1, 0, true,  stA(0, p0 + 4), -1);
    PH(1, 1, false, stB(1, p0 + 5), VMS);
    PH(2, 0, true,  stA(1, p0 + 5), -1);
    PH(2, 1, false, stB(2, p0 + 6), -1);
    PH(3, 0, true,  stA(2, p0 + 6), -1);
    PH(3, 1, false, stB(3, p0 + 7), VMS);
  }
  PH(0, 0, true,  stA(3, 63), -1);
  PH(0, 1, false, (void)0, -1);
  PH(1, 0, true,  (void)0, -1);
  PH(1, 1, false, (void)0, 0);
  PH(2, 0, true,  (void)0, -1);
  PH(2, 1, false, (void)0, -1);
  PH(3, 0, true,  (void)0, -1);
  PH(3, 1, false, (void)0, -1);
#undef PH

#pragma unroll
  for (int mig = 0; mig < 8; ++mig) {
#pragma unroll
    for (int j = 0; j < 4; ++j) {
      int row = m0 + wm * 128 + mig * 16 + lg * 4 + j;
#pragma unroll
      for (int ni = 0; ni < NF; ++ni) {
        int col = n0 + wn * (NF * 16) + ni * 16 + lr;
        float v = acc[mig][ni][j];
        if (F32OUT) ((float*)Cp)[(size_t)row * N + col] = v;
        else        ((unsigned short*)Cp)[(size_t)row * N + col] = f2b(v);
      }
    }
  }
}

// ---- fused K-RoPE (in place) + V transpose -> vt[b][kvh][d=64][t=1024] ----
__global__ __launch_bounds__(256)
void ropekv_kernel(unsigned short* __restrict__ qkv,
                   const float* __restrict__ cosb, const float* __restrict__ sinb,
                   unsigned short* __restrict__ vt) {
  const int tt0 = blockIdx.x * 64;
  const int kvh = blockIdx.y;
  const int b   = blockIdx.z;
  const int tid = threadIdx.x;

  {
    int r = tid >> 2, c0 = (tid & 3) * 16;
    int t = tt0 + r;
    unsigned short* kp = qkv + (size_t)(b * 1024 + t) * 3072 + 2048 + kvh * 64 + c0;
    const float* cb = cosb + t * 32 + c0 / 2;
    const float* sb = sinb + t * 32 + c0 / 2;
    ushort8v x0 = *(const ushort8v*)kp;
    ushort8v x1 = *(const ushort8v*)(kp + 8);
    float8v c = *(const float8v*)cb;
    float8v s = *(const float8v*)sb;
    ushort8v o0, o1;
#pragma unroll
    for (int j = 0; j < 4; ++j) {
      float xr = b2f(x0[2 * j]), xi = b2f(x0[2 * j + 1]);
      o0[2 * j]     = f2b(xr * c[j] - xi * s[j]);
      o0[2 * j + 1] = f2b(xr * s[j] + xi * c[j]);
    }
#pragma unroll
    for (int j = 0; j < 4; ++j) {
      float xr = b2f(x1[2 * j]), xi = b2f(x1[2 * j + 1]);
      o1[2 * j]     = f2b(xr * c[4 + j] - xi * s[4 + j]);
      o1[2 * j + 1] = f2b(xr * s[4 + j] + xi * c[4 + j]);
    }
    *(ushort8v*)kp = o0;
    *(ushort8v*)(kp + 8) = o1;
  }

  __shared__ unsigned short lT[64 * 68];
#pragma unroll
  for (int i = 0; i < 2; ++i) {
    int r = i * 32 + (tid >> 3), c = (tid & 7) * 8;
    const unsigned short* src = qkv + (size_t)(b * 1024 + tt0 + r) * 3072 + 2560 + kvh * 64 + c;
    ushort8v v = *(const ushort8v*)src;
    ushort4v a, b4;
#pragma unroll
    for (int j = 0; j < 4; ++j) { a[j] = v[j]; b4[j] = v[j + 4]; }
    *(ushort4v*)&lT[r * 68 + c]     = a;
    *(ushort4v*)&lT[r * 68 + c + 4] = b4;
  }
  __syncthreads();
#pragma unroll
  for (int i = 0; i < 2; ++i) {
    int d = tid & 63;
    int tt = i * 4 + (tid >> 6);
    ushort8v o;
#pragma unroll
    for (int j = 0; j < 8; ++j) o[j] = lT[(tt * 8 + j) * 68 + d];
    *(ushort8v*)&vt[((size_t)((b * 8 + kvh) * 64 + d)) * 1024 + tt0 + tt * 8] = o;
  }
}

// ---- flash attention: 8 waves = {hi,lo} q-tiles x 4 heads, one state/wave ----
// grid (16,8,4) XCD-swizzled, 512 threads. Waves 0-3: q-tile 31-bx (heads 0-3);
// waves 4-7: q-tile bx. Shared K/V staging (lo kv-range is a subset of hi's).
// 2 blocks/CU x 8 waves = 16 waves/CU (4/SIMD) to hide the softmax VALU chain.
__global__ __launch_bounds__(512, 4)
void attn_kernel(const unsigned short* __restrict__ qkv, const unsigned short* __restrict__ vt,
                 const float* __restrict__ cosb, const float* __restrict__ sinb,
                 unsigned short* __restrict__ ob) {
  const int flat = (blockIdx.z * 8 + blockIdx.y) * 16 + blockIdx.x;
  const int swzb = (flat & 7) * 64 + (flat >> 3);
  const int bx = swzb & 15, kvh = (swzb >> 4) & 7, b = swzb >> 7;

  const int tid = threadIdx.x, wave = tid >> 6, lane = tid & 63;
  const int l31 = lane & 31, hi = lane >> 5;
  const int wq = wave & 3, wh = wave >> 2;          // wh: 0 = hi q-tile, 1 = lo
  const int h = kvh * 4 + wq;

  const int qth = 31 - bx, qtl = bx;
  const int nth = qth / 4 + 1, ntl = qtl / 4 + 1;   // KVBLK=128 tile counts
  const int q0 = (wh ? qtl : qth) * 32;
  const int nt = wh ? ntl : nth;                    // this wave's compute tiles

  __shared__ unsigned short lK[2][128 * 64];
  __shared__ unsigned short lVt[2][64 * 128];

  // Q fragment load with fused RoPE: lane holds Q[q0+l31][dk*16 + hi*8 + i]
  bf16x8 qf[4];
  {
    int t = q0 + l31;
    const unsigned short* qp = qkv + (size_t)(b * 1024 + t) * 3072 + h * 64;
#pragma unroll
    for (int dk = 0; dk < 4; ++dk) {
      ushort8v q = *(const ushort8v*)(qp + dk * 16 + hi * 8);
      f32x4 c4 = *(const f32x4*)(cosb + t * 32 + dk * 8 + hi * 4);
      f32x4 s4 = *(const f32x4*)(sinb + t * 32 + dk * 8 + hi * 4);
      ushort8v o;
#pragma unroll
      for (int j = 0; j < 4; ++j) {
        float xr = b2f(q[2 * j]), xi = b2f(q[2 * j + 1]);
        o[2 * j]     = f2b(xr * c4[j] - xi * s4[j]);
        o[2 * j + 1] = f2b(xr * s4[j] + xi * c4[j]);
      }
      qf[dk] = __builtin_bit_cast(bf16x8, o);
    }
  }

  const unsigned short* kg = qkv + (size_t)(b * 1024) * 3072 + 2048 + kvh * 64;
  const unsigned short* vg = vt + (size_t)(b * 8 + kvh) * 64 * 1024;

  // 512-thread staging: K rows 0..127 (2 issues), V rows 0..63 (2 issues);
  // per-wave LDS addr is base + lane*16 (linear) as global_load_lds requires.
  auto stage = [&](int kvb, int bi) {
    const int sr  = tid >> 3;          // 0..63
    const int scb = (tid & 7) * 16;
#pragma unroll
    for (int i = 0; i < 2; ++i) {
      int r = i * 64 + sr;
      int cb = scb ^ ((r & 7) << 4);
      async16(kg + (size_t)(kvb + r) * 3072 + (cb >> 1), &lK[bi][r * 64 + (scb >> 1)]);
    }
    const int rv0 = tid >> 4;          // 0..31
    const int scv = (tid & 15) * 16;
#pragma unroll
    for (int i = 0; i < 2; ++i) {
      int rv = i * 32 + rv0;
      int cbv = scv ^ ((rv & 15) << 4);
      async16(vg + (size_t)rv * 1024 + kvb + (cbv >> 1), &lVt[bi][rv * 128 + (scv >> 1)]);
    }
  };

  f32x16 oacc[2] = {};
  float m2 = -3e38f, l_run = 0.f;

  const float SC = 0.125f * 1.44269504f;

  auto chunk64 = [&](int cur, int ckvb, int c, bool lastT) {
    f32x16 sd[2] = {};
    __builtin_amdgcn_s_setprio(1);
#pragma unroll
    for (int s = 0; s < 2; ++s) {
      const int krow = c * 64 + s * 32 + l31;
      const char* kr = (const char*)lK[cur] + krow * 128;
      const int swz = (krow & 7) << 4;
#pragma unroll
      for (int dk = 0; dk < 4; ++dk) {
        bf16x8 kf = *(const bf16x8*)(kr + ((dk * 32 + hi * 16) ^ swz));
        sd[s] = __builtin_amdgcn_mfma_f32_32x32x16_bf16(kf, qf[dk], sd[s], 0, 0, 0);
      }
    }
    __builtin_amdgcn_s_setprio(0);

#pragma unroll
    for (int s = 0; s < 2; ++s)
#pragma unroll
      for (int r = 0; r < 16; ++r) {
        float v = sd[s][r] * SC;
        if (lastT) {
          int kvg = ckvb + s * 32 + (r & 3) + 8 * (r >> 2) + 4 * hi;
          if (kvg > q0 + l31) v = -3e38f;
        }
        sd[s][r] = v;
      }
    float pm = sd[0][0];
#pragma unroll
    for (int s = 0; s < 2; ++s)
#pragma unroll
      for (int r = 0; r < 16; ++r) pm = fmaxf(pm, sd[s][r]);
    pm = fmaxf(pm, __shfl_xor(pm, 32));
    if (!__all(pm <= m2 + 11.0f)) {          // T13 defer-max (log2 domain)
      float mnew = fmaxf(m2, pm);
      float alpha = exp2f(m2 - mnew);
      m2 = mnew;
      l_run *= alpha;
#pragma unroll
      for (int db = 0; db < 2; ++db)
#pragma unroll
        for (int r = 0; r < 16; ++r) oacc[db][r] *= alpha;
    }
    float tsum = 0.f;
#pragma unroll
    for (int s = 0; s < 2; ++s)
#pragma unroll
      for (int r = 0; r < 16; ++r) { float p = exp2f(sd[s][r] - m2); sd[s][r] = p; tsum += p; }
    tsum += __shfl_xor(tsum, 32);
    l_run += tsum;

    bf16x8 pf[2][2];
#pragma unroll
    for (int s = 0; s < 2; ++s)
#pragma unroll
      for (int kc = 0; kc < 2; ++kc) {
        unsigned int cA = cvtpk(sd[s][8 * kc + 0], sd[s][8 * kc + 1]);
        unsigned int cB = cvtpk(sd[s][8 * kc + 4], sd[s][8 * kc + 5]);
        unsigned int cC = cvtpk(sd[s][8 * kc + 2], sd[s][8 * kc + 3]);
        unsigned int cD = cvtpk(sd[s][8 * kc + 6], sd[s][8 * kc + 7]);
        unsigned int xA = __shfl_xor(cA, 32), xB = __shfl_xor(cB, 32);
        unsigned int xC = __shfl_xor(cC, 32), xD = __shfl_xor(cD, 32);
        uint4v u;
        u[0] = hi ? xB : cA;
        u[1] = hi ? xD : cC;
        u[2] = hi ? cB : xA;
        u[3] = hi ? cD : xC;
        pf[s][kc] = __builtin_bit_cast(bf16x8, u);
      }

    __builtin_amdgcn_s_setprio(1);
#pragma unroll
    for (int db = 0; db < 2; ++db) {
      const int row = db * 32 + l31;
      const char* vr = (const char*)lVt[cur] + row * 256;
      const int vswz = (row & 15) << 4;
#pragma unroll
      for (int s = 0; s < 2; ++s)
#pragma unroll
        for (int kc = 0; kc < 2; ++kc) {
          bf16x8 vf = *(const bf16x8*)(vr + ((c * 128 + s * 64 + kc * 32 + hi * 16) ^ vswz));
          oacc[db] = __builtin_amdgcn_mfma_f32_32x32x16_bf16(vf, pf[s][kc], oacc[db], 0, 0, 0);
        }
    }
    __builtin_amdgcn_s_setprio(0);
  };

  stage(0, 0);
  __syncthreads();

  for (int j = 0; j < nth; ++j) {
    const int cur = j & 1;
    if (j + 1 < nth) stage((j + 1) * 128, cur ^ 1);   // issue-early (T14)
    const int kvb = j * 128;

    if (j < nt) {                                     // wave-uniform
      const bool lastT = (j == nt - 1);
#pragma unroll 1
      for (int c = 0; c < 2; ++c) {
        if (kvb + c * 64 > q0 + 31) continue;         // fully-masked chunk
        chunk64(cur, kvb + c * 64, c, lastT);
      }
    }
    __syncthreads();   // drains prefetch + buffer handoff
  }

  // epilogue: O^T row r -> d = (r&3)+8*(r>>2)+4*hi, col = q = l31
  {
    float inv = 1.0f / l_run;
    unsigned short* orow = ob + (size_t)(b * 1024 + q0 + l31) * 2048 + h * 64;
#pragma unroll
    for (int db = 0; db < 2; ++db)
#pragma unroll
      for (int g = 0; g < 4; ++g) {
        int d0 = db * 32 + 8 * g + 4 * hi;
        ushort4v o;
#pragma unroll
        for (int j = 0; j < 4; ++j) o[j] = f2b(oacc[db][4 * g + j] * inv);
        *(ushort4v*)(orow + d0) = o;
      }
  }
}

extern "C" void kernel_launch(void* const* d_in, const int* in_sizes, int n_in,
                              void* d_out, int out_size, void* d_ws, size_t ws_size,
                              hipStream_t stream) {
  const float* input = (const float*)d_in[0];
  const float* fcos  = (const float*)d_in[1];
  const float* fsin  = (const float*)d_in[2];
  const float* wq = (const float*)d_in[4];
  const float* wk = (const float*)d_in[5];
  const float* wv = (const float*)d_in[6];
  const float* wo = (const float*)d_in[7];
  float* out = (float*)d_out;

  unsigned short* xb   = (unsigned short*)d_ws;               // 4096 x 2048 (dead after gemm1)
  unsigned short* wqkv = xb + (size_t)4096 * 2048;            // 3072 x 2048
  unsigned short* wob  = wqkv + (size_t)3072 * 2048;          // 2048 x 2048
  unsigned short* qkv  = wob + (size_t)2048 * 2048;           // 4096 x 3072
  unsigned short* ob   = qkv + (size_t)4096 * 3072;           // 4096 x 2048
  unsigned short* vtb  = xb;                                  // 4*8*64*1024 (reuses xb)

  hipFuncSetAttribute((const void*)&gemmQ192,
                      hipFuncAttributeMaxDynamicSharedMemorySize, 114688);
  hipFuncSetAttribute((const void*)&gemm8p<true, 128, 16, 16>,
                      hipFuncAttributeMaxDynamicSharedMemorySize, 98304);

  CvtArgs ca;
  ca.src[0] = input; ca.dst[0] = xb;                        ca.n[0] = (long)4096 * 2048;
  ca.src[1] = wq;    ca.dst[1] = wqkv;                      ca.n[1] = (long)2048 * 2048;
  ca.src[2] = wk;    ca.dst[2] = wqkv + (size_t)2048 * 2048; ca.n[2] = (long)512 * 2048;
  ca.src[3] = wv;    ca.dst[3] = wqkv + (size_t)2560 * 2048; ca.n[3] = (long)512 * 2048;
  ca.src[4] = wo;    ca.dst[4] = wob;                       ca.n[4] = (long)2048 * 2048;
  hipLaunchKernelGGL(cvt5_kernel, dim3(2048), dim3(256), 0, stream, ca);

  // fused QKV projection: qkv = xb @ wqkv^T  (M=4096, N=3072, K=2048), full-chip grid
  hipLaunchKernelGGL(gemmQ192, dim3(16, 16), dim3(512), 114688,
                     stream, xb, wqkv, qkv);

  // K-RoPE in place + V transpose
  hipLaunchKernelGGL(ropekv_kernel, dim3(16, 8, 4), dim3(256), 0, stream,
                     qkv, fcos, fsin, vtb);

  // flash attention (Q-RoPE fused) -> ob (b,t,h,d) bf16
  hipLaunchKernelGGL(attn_kernel, dim3(16, 8, 4), dim3(512), 0, stream,
                     qkv, vtb, fcos, fsin, ob);

  // output projection: out = ob @ wob^T  (M=4096, N=2048, K=2048), fp32 out
  hipLaunchKernelGGL((gemm8p<true, 128, 16, 16>), dim3(16, 16), dim3(512), 98304,
                     stream, ob, wob, (void*)out, 2048);
}

// Round 13
// 157.041 us; speedup vs baseline: 1.0938x; 1.0414x over previous
//
#include <hip/hip_runtime.h>
#include <cstdint>

// ---- types ----
typedef __bf16 bf16x8 __attribute__((ext_vector_type(8)));
typedef float  f32x4  __attribute__((ext_vector_type(4)));
typedef float  f32x16 __attribute__((ext_vector_type(16)));
typedef float  float8v __attribute__((ext_vector_type(8)));
typedef unsigned short ushort8v __attribute__((ext_vector_type(8)));
typedef unsigned short ushort4v __attribute__((ext_vector_type(4)));
typedef unsigned int   uint4v   __attribute__((ext_vector_type(4)));

__device__ __forceinline__ unsigned short f2b(float f) {
  uint32_t u = __builtin_bit_cast(uint32_t, f);
  u += 0x7FFFu + ((u >> 16) & 1u);     // round-to-nearest-even
  return (unsigned short)(u >> 16);
}
__device__ __forceinline__ float b2f(unsigned short h) {
  uint32_t u = ((uint32_t)h) << 16;
  return __builtin_bit_cast(float, u);
}
__device__ __forceinline__ unsigned int cvtpk(float lo, float hi_) {
  unsigned int r;
  asm("v_cvt_pk_bf16_f32 %0, %1, %2" : "=v"(r) : "v"(lo), "v"(hi_));
  return r;
}

__device__ __forceinline__ void async16(const void* g, void* l) {
  __builtin_amdgcn_global_load_lds(
      (const __attribute__((address_space(1))) void*)g,
      (__attribute__((address_space(3))) void*)l, 16, 0, 0);
}

// s_waitcnt immediates (gfx9 encoding): vmcnt[3:0]|[15:14], expcnt[6:4], lgkmcnt[11:8]
#define WAITVM(N)  __builtin_amdgcn_s_waitcnt(0x0F70 | ((N) & 15))

// ---- fused fp32 -> bf16 convert, 5 segments in one launch ----
struct CvtArgs {
  const float* src[5];
  unsigned short* dst[5];
  long n[5];
};
__global__ void cvt5_kernel(CvtArgs a) {
  long base = (long)blockIdx.x * blockDim.x + threadIdx.x;
  long gstride = (long)gridDim.x * blockDim.x;
#pragma unroll 1
  for (int sg = 0; sg < 5; ++sg) {
    const float* s = a.src[sg];
    unsigned short* d = a.dst[sg];
    long n8 = a.n[sg] >> 3;
    for (long i = base; i < n8; i += gstride) {
      float8v f = *(const float8v*)(s + i * 8);
      ushort8v o;
#pragma unroll
      for (int j = 0; j < 8; ++j) o[j] = f2b(f[j]);
      *(ushort8v*)(d + i * 8) = o;
    }
  }
}

// ---- QKV GEMM, full-chip grid: BN=192, 16x16=256 blocks (r11, unchanged) ----
__global__ __launch_bounds__(512, 2)
void gemmQ192(const unsigned short* __restrict__ Ag, const unsigned short* __restrict__ Wg,
              unsigned short* __restrict__ Cp) {
  constexpr int K = 2048;
  constexpr int NF = 3;
  constexpr int ASLOT = 16384;
  constexpr int BSLOT = 24576;
  constexpr int N = 3072;

  extern __shared__ char lds_c[];

  const int tid = threadIdx.x;
  const int wave = tid >> 6, lane = tid & 63;
  const int wm = wave >> 2, wn = wave & 3;
  const int lr = lane & 15, lg = lane >> 4;

  const int flat = blockIdx.y * 16 + blockIdx.x;
  const int swz = (flat & 7) * 32 + (flat >> 3);
  const int m0 = (swz >> 4) * 256, n0 = (swz & 15) * 192;

  const int laneSw = (lr >> 1) * 128 + (((((lr & 1) << 2) | lg) ^ (lr >> 1)) << 4);
  const int aoff = wm * 8192 + laneSw;

  int bByte[NF], bR7[NF];
#pragma unroll
  for (int ni = 0; ni < NF; ++ni) {
    int row = wn * 48 + ni * 16 + lr;
    bByte[ni] = row * 128;
    bR7[ni] = row & 7;
  }

  f32x4 acc[8][NF] = {};
  bf16x8 af[4], bf[NF];

  auto stA = [&](int slot, int s) {
    char* sl = lds_c + slot * ASLOT;
    const int kc = s * 32;
#pragma unroll
    for (int j = 0; j < 2; ++j) {
      int q = (tid + 512 * j) * 16;
      int R = q >> 7, g2L = ((q >> 4) & 7) ^ (R & 7);
      int row = R * 2 + (g2L >> 2), kg = g2L & 3;
      async16(Ag + (size_t)(m0 + row) * K + kc + kg * 8, sl + q);
    }
  };
  auto stB = [&](int slot, int T) {
    char* sl = lds_c + 4 * ASLOT + slot * BSLOT;
    const int kc = T * 64;
#pragma unroll
    for (int j = 0; j < 3; ++j) {
      int q = (tid + 512 * j) * 16;
      int row = q >> 7, c = (q >> 4) & 7;
      async16(Wg + (size_t)(n0 + row) * K + kc + ((c ^ (row & 7)) * 8), sl + q);
    }
  };

#define PH(SA, SB, MH, KH, RDB, STG, VM)                                      \
  {                                                                           \
    const char* As_ = lds_c + (SA) * ASLOT;                                   \
    _Pragma("unroll") for (int mi = 0; mi < 4; ++mi)                          \
      af[mi] = *(const bf16x8*)(As_ + aoff + ((MH) * 4 + mi) * 1024);         \
    if (RDB) {                                                                \
      const char* Bs_ = lds_c + 4 * ASLOT + (SB) * BSLOT;                     \
      _Pragma("unroll") for (int ni = 0; ni < NF; ++ni)                       \
        bf[ni] = *(const bf16x8*)(Bs_ + bByte[ni] +                           \
                                  (((((KH) << 2) | lg) ^ bR7[ni]) << 4));     \
    }                                                                         \
    STG;                                                                      \
    if ((VM) >= 0) WAITVM(VM);                                                \
    __builtin_amdgcn_s_barrier();                                             \
    __builtin_amdgcn_s_setprio(1);                                            \
    _Pragma("unroll") for (int mi = 0; mi < 4; ++mi)                          \
      _Pragma("unroll") for (int ni = 0; ni < NF; ++ni)                       \
        acc[(MH) * 4 + mi][ni] = __builtin_amdgcn_mfma_f32_16x16x32_bf16(     \
            af[mi], bf[ni], acc[(MH) * 4 + mi][ni], 0, 0, 0);                 \
    __builtin_amdgcn_s_setprio(0);                                            \
    __builtin_amdgcn_s_barrier();                                             \
  }

  stB(0, 0); stA(0, 0); stA(1, 1); stB(1, 1); stA(2, 2);
  WAITVM(5);
  __builtin_amdgcn_s_barrier();

  for (int t2 = 0; t2 < 30; t2 += 2) {
    PH(0, 0, 0, 0, true,  stA(3, 2 * t2 + 3), -1);
    PH(0, 0, 1, 0, false, (void)0, -1);
    PH(1, 0, 0, 1, true,  stA(0, 2 * t2 + 4), -1);
    PH(1, 0, 1, 1, false, stB(0, t2 + 2), 5);
    PH(2, 1, 0, 0, true,  stA(1, 2 * t2 + 5), -1);
    PH(2, 1, 1, 0, false, (void)0, -1);
    PH(3, 1, 0, 1, true,  stA(2, 2 * t2 + 6), -1);
    PH(3, 1, 1, 1, false, stB(1, t2 + 3), 5);
  }
  PH(0, 0, 0, 0, true,  stA(3, 63), -1);
  PH(0, 0, 1, 0, false, (void)0, -1);
  PH(1, 0, 0, 1, true,  (void)0, -1);
  PH(1, 0, 1, 1, false, (void)0, 0);
  PH(2, 1, 0, 0, true,  (void)0, -1);
  PH(2, 1, 1, 0, false, (void)0, -1);
  PH(3, 1, 0, 1, true,  (void)0, -1);
  PH(3, 1, 1, 1, false, (void)0, -1);
#undef PH

#pragma unroll
  for (int mig = 0; mig < 8; ++mig) {
#pragma unroll
    for (int j = 0; j < 4; ++j) {
      int row = m0 + wm * 128 + mig * 16 + lg * 4 + j;
#pragma unroll
      for (int ni = 0; ni < NF; ++ni) {
        int col = n0 + wn * 48 + ni * 16 + lr;
        Cp[(size_t)row * N + col] = f2b(acc[mig][ni][j]);
      }
    }
  }
}

// ---- 8-phase GEMM (r10 structure) — used for the WO projection ----
template<bool F32OUT, int BN, int GX, int GY>
__global__ __launch_bounds__(512, 2)
void gemm8p(const unsigned short* __restrict__ Ag, const unsigned short* __restrict__ Wg,
            void* __restrict__ Cp, int N) {
  constexpr int K = 2048;
  constexpr int BM = 256;
  constexpr int NF = BN / 64;
  constexpr int AL = 2;
  constexpr int BL = BN / 128;
  constexpr int VMS = 2 * BL + AL;
  constexpr int ASLOT = BM * 64;
  constexpr int BSLOT = BN * 64;
  constexpr int NWG = GX * GY;
  constexpr int CPX = NWG / 8;

  extern __shared__ char lds_c[];

  const int tid = threadIdx.x;
  const int wave = tid >> 6, lane = tid & 63;
  const int wm = wave >> 2, wn = wave & 3;
  const int lr = lane & 15, lg = lane >> 4;

  const int flat = blockIdx.y * GX + blockIdx.x;
  const int swz = (flat & 7) * CPX + (flat >> 3);
  const int m0 = (swz / GX) * BM, n0 = (swz % GX) * BN;

  const int laneSw = (lr >> 1) * 128 + (((((lr & 1) << 2) | lg) ^ (lr >> 1)) << 4);
  const int aoff = wm * 128 * 64 + laneSw;
  const int boff = wn * NF * 1024 + laneSw;

  f32x4 acc[8][NF] = {};
  bf16x8 af[4], bf[NF];

  auto stA = [&](int slot, int s) {
    char* sl = lds_c + slot * ASLOT;
    const int kc = s * 32;
#pragma unroll
    for (int j = 0; j < AL; ++j) {
      int q = (tid + 512 * j) * 16;
      int R = q >> 7, g2L = ((q >> 4) & 7) ^ (R & 7);
      int row = R * 2 + (g2L >> 2), kg = g2L & 3;
      async16(Ag + (size_t)(m0 + row) * K + kc + kg * 8, sl + q);
    }
  };
  auto stB = [&](int slot, int s) {
    char* sl = lds_c + 4 * ASLOT + slot * BSLOT;
    const int kc = s * 32;
#pragma unroll
    for (int j = 0; j < BL; ++j) {
      int q = (tid + 512 * j) * 16;
      int R = q >> 7, g2L = ((q >> 4) & 7) ^ (R & 7);
      int row = R * 2 + (g2L >> 2), kg = g2L & 3;
      async16(Wg + (size_t)(n0 + row) * K + kc + kg * 8, sl + q);
    }
  };

#define PH(RSLOT, MH, RDB, STG, VM)                                           \
  {                                                                           \
    const char* As_ = lds_c + (RSLOT) * ASLOT;                                \
    _Pragma("unroll") for (int mi = 0; mi < 4; ++mi)                          \
      af[mi] = *(const bf16x8*)(As_ + aoff + ((MH) * 4 + mi) * 1024);         \
    if (RDB) {                                                                \
      const char* Bs_ = lds_c + 4 * ASLOT + (RSLOT) * BSLOT;                  \
      _Pragma("unroll") for (int ni = 0; ni < NF; ++ni)                       \
        bf[ni] = *(const bf16x8*)(Bs_ + boff + ni * 1024);                    \
    }                                                                         \
    STG;                                                                      \
    if ((VM) >= 0) WAITVM(VM);                                                \
    __builtin_amdgcn_s_barrier();                                             \
    __builtin_amdgcn_s_setprio(1);                                            \
    _Pragma("unroll") for (int mi = 0; mi < 4; ++mi)                          \
      _Pragma("unroll") for (int ni = 0; ni < NF; ++ni)                       \
        acc[(MH) * 4 + mi][ni] = __builtin_amdgcn_mfma_f32_16x16x32_bf16(     \
            af[mi], bf[ni], acc[(MH) * 4 + mi][ni], 0, 0, 0);                 \
    __builtin_amdgcn_s_setprio(0);                                            \
    __builtin_amdgcn_s_barrier();                                             \
  }

  stB(0, 0); stA(0, 0); stB(1, 1); stA(1, 1); stB(2, 2); stA(2, 2); stB(3, 3);
  WAITVM(VMS);
  __builtin_amdgcn_s_barrier();

  for (int T = 0; T < 30; T += 2) {
    const int p0 = 2 * T;
    PH(0, 0, true,  stA(3, p0 + 3), -1);
    PH(0, 1, false, stB(0, p0 + 4), -1);
    PH(1, 0, true,  stA(0, p0 + 4), -1);
    PH(1, 1, false, stB(1, p0 + 5), VMS);
    PH(2, 0, true,  stA(1, p0 + 5), -1);
    PH(2, 1, false, stB(2, p0 + 6), -1);
    PH(3, 0, true,  stA(2, p0 + 6), -1);
    PH(3, 1, false, stB(3, p0 + 7), VMS);
  }
  PH(0, 0, true,  stA(3, 63), -1);
  PH(0, 1, false, (void)0, -1);
  PH(1, 0, true,  (void)0, -1);
  PH(1, 1, false, (void)0, 0);
  PH(2, 0, true,  (void)0, -1);
  PH(2, 1, false, (void)0, -1);
  PH(3, 0, true,  (void)0, -1);
  PH(3, 1, false, (void)0, -1);
#undef PH

#pragma unroll
  for (int mig = 0; mig < 8; ++mig) {
#pragma unroll
    for (int j = 0; j < 4; ++j) {
      int row = m0 + wm * 128 + mig * 16 + lg * 4 + j;
#pragma unroll
      for (int ni = 0; ni < NF; ++ni) {
        int col = n0 + wn * (NF * 16) + ni * 16 + lr;
        float v = acc[mig][ni][j];
        if (F32OUT) ((float*)Cp)[(size_t)row * N + col] = v;
        else        ((unsigned short*)Cp)[(size_t)row * N + col] = f2b(v);
      }
    }
  }
}

// ---- fused K-RoPE (in place) + V transpose -> vt[b][kvh][d=64][t=1024] ----
__global__ __launch_bounds__(256)
void ropekv_kernel(unsigned short* __restrict__ qkv,
                   const float* __restrict__ cosb, const float* __restrict__ sinb,
                   unsigned short* __restrict__ vt) {
  const int tt0 = blockIdx.x * 64;
  const int kvh = blockIdx.y;
  const int b   = blockIdx.z;
  const int tid = threadIdx.x;

  {
    int r = tid >> 2, c0 = (tid & 3) * 16;
    int t = tt0 + r;
    unsigned short* kp = qkv + (size_t)(b * 1024 + t) * 3072 + 2048 + kvh * 64 + c0;
    const float* cb = cosb + t * 32 + c0 / 2;
    const float* sb = sinb + t * 32 + c0 / 2;
    ushort8v x0 = *(const ushort8v*)kp;
    ushort8v x1 = *(const ushort8v*)(kp + 8);
    float8v c = *(const float8v*)cb;
    float8v s = *(const float8v*)sb;
    ushort8v o0, o1;
#pragma unroll
    for (int j = 0; j < 4; ++j) {
      float xr = b2f(x0[2 * j]), xi = b2f(x0[2 * j + 1]);
      o0[2 * j]     = f2b(xr * c[j] - xi * s[j]);
      o0[2 * j + 1] = f2b(xr * s[j] + xi * c[j]);
    }
#pragma unroll
    for (int j = 0; j < 4; ++j) {
      float xr = b2f(x1[2 * j]), xi = b2f(x1[2 * j + 1]);
      o1[2 * j]     = f2b(xr * c[4 + j] - xi * s[4 + j]);
      o1[2 * j + 1] = f2b(xr * s[4 + j] + xi * c[4 + j]);
    }
    *(ushort8v*)kp = o0;
    *(ushort8v*)(kp + 8) = o1;
  }

  __shared__ unsigned short lT[64 * 68];
#pragma unroll
  for (int i = 0; i < 2; ++i) {
    int r = i * 32 + (tid >> 3), c = (tid & 7) * 8;
    const unsigned short* src = qkv + (size_t)(b * 1024 + tt0 + r) * 3072 + 2560 + kvh * 64 + c;
    ushort8v v = *(const ushort8v*)src;
    ushort4v a, b4;
#pragma unroll
    for (int j = 0; j < 4; ++j) { a[j] = v[j]; b4[j] = v[j + 4]; }
    *(ushort4v*)&lT[r * 68 + c]     = a;
    *(ushort4v*)&lT[r * 68 + c + 4] = b4;
  }
  __syncthreads();
#pragma unroll
  for (int i = 0; i < 2; ++i) {
    int d = tid & 63;
    int tt = i * 4 + (tid >> 6);
    ushort8v o;
#pragma unroll
    for (int j = 0; j < 8; ++j) o[j] = lT[(tt * 8 + j) * 68 + d];
    *(ushort8v*)&vt[((size_t)((b * 8 + kvh) * 64 + d)) * 1024 + tt0 + tt * 8] = o;
  }
}

// ---- flash attention: 8 waves = {hi,lo} q-tiles x 4 heads, KVBLK=64 ----
// grid (16,8,4) XCD-swizzled, 512 threads. LDS 32KB (dbuf 64x64 K + 64x64 Vt)
// -> 4 blocks/CU = 32 waves/CU (8/SIMD) to hide the softmax VALU chain.
// SC*log2e folded into Q at load; mask pass only on the last tile.
__global__ __launch_bounds__(512, 4)
void attn_kernel(const unsigned short* __restrict__ qkv, const unsigned short* __restrict__ vt,
                 const float* __restrict__ cosb, const float* __restrict__ sinb,
                 unsigned short* __restrict__ ob) {
  const int flat = (blockIdx.z * 8 + blockIdx.y) * 16 + blockIdx.x;
  const int swzb = (flat & 7) * 64 + (flat >> 3);
  const int bx = swzb & 15, kvh = (swzb >> 4) & 7, b = swzb >> 7;

  const int tid = threadIdx.x, wave = tid >> 6, lane = tid & 63;
  const int l31 = lane & 31, hi = lane >> 5;
  const int wq = wave & 3, wh = wave >> 2;          // wh: 0 = hi q-tile, 1 = lo
  const int h = kvh * 4 + wq;

  const int qth = 31 - bx, qtl = bx;
  const int nth = qth / 2 + 1, ntl = qtl / 2 + 1;   // KVBLK=64 tile counts
  const int q0 = (wh ? qtl : qth) * 32;
  const int nt = wh ? ntl : nth;

  __shared__ unsigned short lK[2][64 * 64];
  __shared__ unsigned short lVt[2][64 * 64];

  // Q fragment load with fused RoPE and folded softmax scale (0.125 * log2e)
  const float SC = 0.125f * 1.44269504f;
  bf16x8 qf[4];
  {
    int t = q0 + l31;
    const unsigned short* qp = qkv + (size_t)(b * 1024 + t) * 3072 + h * 64;
#pragma unroll
    for (int dk = 0; dk < 4; ++dk) {
      ushort8v q = *(const ushort8v*)(qp + dk * 16 + hi * 8);
      f32x4 c4 = *(const f32x4*)(cosb + t * 32 + dk * 8 + hi * 4);
      f32x4 s4 = *(const f32x4*)(sinb + t * 32 + dk * 8 + hi * 4);
      ushort8v o;
#pragma unroll
      for (int j = 0; j < 4; ++j) {
        float xr = b2f(q[2 * j]), xi = b2f(q[2 * j + 1]);
        o[2 * j]     = f2b((xr * c4[j] - xi * s4[j]) * SC);
        o[2 * j + 1] = f2b((xr * s4[j] + xi * c4[j]) * SC);
      }
      qf[dk] = __builtin_bit_cast(bf16x8, o);
    }
  }

  const unsigned short* kg = qkv + (size_t)(b * 1024) * 3072 + 2048 + kvh * 64;
  const unsigned short* vg = vt + (size_t)(b * 8 + kvh) * 64 * 1024;

  // 512-thread staging: K rows 0..63 (1 issue), Vt rows 0..63 (1 issue);
  // per-wave LDS dest is base + lane*16 (linear) as global_load_lds requires.
  auto stage = [&](int kvb, int bi) {
    const int sr  = tid >> 3;          // 0..63
    const int scb = (tid & 7) * 16;    // 0..112 byte
    {
      int cb = scb ^ ((sr & 7) << 4);
      async16(kg + (size_t)(kvb + sr) * 3072 + (cb >> 1), &lK[bi][sr * 64 + (scb >> 1)]);
    }
    {
      int cbv = scb ^ ((sr & 7) << 4);
      async16(vg + (size_t)sr * 1024 + kvb + (cbv >> 1), &lVt[bi][sr * 64 + (scb >> 1)]);
    }
  };

  f32x16 oacc[2] = {};
  float m2 = -3e38f, l_run = 0.f;

  auto chunk64 = [&](int cur, int ckvb, bool lastT) {
    f32x16 sd[2] = {};
    __builtin_amdgcn_s_setprio(1);
#pragma unroll
    for (int s = 0; s < 2; ++s) {
      const int krow = s * 32 + l31;
      const char* kr = (const char*)lK[cur] + krow * 128;
      const int swz = (krow & 7) << 4;
#pragma unroll
      for (int dk = 0; dk < 4; ++dk) {
        bf16x8 kf = *(const bf16x8*)(kr + ((dk * 32 + hi * 16) ^ swz));
        sd[s] = __builtin_amdgcn_mfma_f32_32x32x16_bf16(kf, qf[dk], sd[s], 0, 0, 0);
      }
    }
    __builtin_amdgcn_s_setprio(0);

    if (lastT) {
#pragma unroll
      for (int s = 0; s < 2; ++s)
#pragma unroll
        for (int r = 0; r < 16; ++r) {
          int kvg = ckvb + s * 32 + (r & 3) + 8 * (r >> 2) + 4 * hi;
          if (kvg > q0 + l31) sd[s][r] = -3e38f;
        }
    }
    float pm = sd[0][0];
#pragma unroll
    for (int s = 0; s < 2; ++s)
#pragma unroll
      for (int r = 0; r < 16; ++r) pm = fmaxf(pm, sd[s][r]);
    pm = fmaxf(pm, __shfl_xor(pm, 32));
    if (!__all(pm <= m2 + 11.0f)) {          // T13 defer-max (log2 domain)
      float mnew = fmaxf(m2, pm);
      float alpha = exp2f(m2 - mnew);
      m2 = mnew;
      l_run *= alpha;
#pragma unroll
      for (int db = 0; db < 2; ++db)
#pragma unroll
        for (int r = 0; r < 16; ++r) oacc[db][r] *= alpha;
    }
    float tsum = 0.f;
#pragma unroll
    for (int s = 0; s < 2; ++s)
#pragma unroll
      for (int r = 0; r < 16; ++r) { float p = exp2f(sd[s][r] - m2); sd[s][r] = p; tsum += p; }
    tsum += __shfl_xor(tsum, 32);
    l_run += tsum;

    bf16x8 pf[2][2];
#pragma unroll
    for (int s = 0; s < 2; ++s)
#pragma unroll
      for (int kc = 0; kc < 2; ++kc) {
        unsigned int cA = cvtpk(sd[s][8 * kc + 0], sd[s][8 * kc + 1]);
        unsigned int cB = cvtpk(sd[s][8 * kc + 4], sd[s][8 * kc + 5]);
        unsigned int cC = cvtpk(sd[s][8 * kc + 2], sd[s][8 * kc + 3]);
        unsigned int cD = cvtpk(sd[s][8 * kc + 6], sd[s][8 * kc + 7]);
        unsigned int xA = __shfl_xor(cA, 32), xB = __shfl_xor(cB, 32);
        unsigned int xC = __shfl_xor(cC, 32), xD = __shfl_xor(cD, 32);
        uint4v u;
        u[0] = hi ? xB : cA;
        u[1] = hi ? xD : cC;
        u[2] = hi ? cB : xA;
        u[3] = hi ? cD : xC;
        pf[s][kc] = __builtin_bit_cast(bf16x8, u);
      }

    __builtin_amdgcn_s_setprio(1);
#pragma unroll
    for (int db = 0; db < 2; ++db) {
      const int row = db * 32 + l31;
      const char* vr = (const char*)lVt[cur] + row * 128;
      const int vswz = (row & 7) << 4;
#pragma unroll
      for (int s = 0; s < 2; ++s)
#pragma unroll
        for (int kc = 0; kc < 2; ++kc) {
          bf16x8 vf = *(const bf16x8*)(vr + ((s * 64 + kc * 32 + hi * 16) ^ vswz));
          oacc[db] = __builtin_amdgcn_mfma_f32_32x32x16_bf16(vf, pf[s][kc], oacc[db], 0, 0, 0);
        }
    }
    __builtin_amdgcn_s_setprio(0);
  };

  stage(0, 0);
  __syncthreads();

  for (int j = 0; j < nth; ++j) {
    const int cur = j & 1;
    if (j + 1 < nth) stage((j + 1) * 64, cur ^ 1);   // issue-early (T14)
    if (j < nt) chunk64(cur, j * 64, j == nt - 1);   // wave-uniform
    __syncthreads();   // drains prefetch + buffer handoff
  }

  // epilogue: O^T row r -> d = (r&3)+8*(r>>2)+4*hi, col = q = l31
  {
    float inv = 1.0f / l_run;
    unsigned short* orow = ob + (size_t)(b * 1024 + q0 + l31) * 2048 + h * 64;
#pragma unroll
    for (int db = 0; db < 2; ++db)
#pragma unroll
      for (int g = 0; g < 4; ++g) {
        int d0 = db * 32 + 8 * g + 4 * hi;
        ushort4v o;
#pragma unroll
        for (int j = 0; j < 4; ++j) o[j] = f2b(oacc[db][4 * g + j] * inv);
        *(ushort4v*)(orow + d0) = o;
      }
  }
}

extern "C" void kernel_launch(void* const* d_in, const int* in_sizes, int n_in,
                              void* d_out, int out_size, void* d_ws, size_t ws_size,
                              hipStream_t stream) {
  const float* input = (const float*)d_in[0];
  const float* fcos  = (const float*)d_in[1];
  const float* fsin  = (const float*)d_in[2];
  const float* wq = (const float*)d_in[4];
  const float* wk = (const float*)d_in[5];
  const float* wv = (const float*)d_in[6];
  const float* wo = (const float*)d_in[7];
  float* out = (float*)d_out;

  unsigned short* xb   = (unsigned short*)d_ws;               // 4096 x 2048 (dead after gemm1)
  unsigned short* wqkv = xb + (size_t)4096 * 2048;            // 3072 x 2048
  unsigned short* wob  = wqkv + (size_t)3072 * 2048;          // 2048 x 2048
  unsigned short* qkv  = wob + (size_t)2048 * 2048;           // 4096 x 3072
  unsigned short* ob   = qkv + (size_t)4096 * 3072;           // 4096 x 2048
  unsigned short* vtb  = xb;                                  // 4*8*64*1024 (reuses xb)

  hipFuncSetAttribute((const void*)&gemmQ192,
                      hipFuncAttributeMaxDynamicSharedMemorySize, 114688);
  hipFuncSetAttribute((const void*)&gemm8p<true, 128, 16, 16>,
                      hipFuncAttributeMaxDynamicSharedMemorySize, 98304);

  CvtArgs ca;
  ca.src[0] = input; ca.dst[0] = xb;                        ca.n[0] = (long)4096 * 2048;
  ca.src[1] = wq;    ca.dst[1] = wqkv;                      ca.n[1] = (long)2048 * 2048;
  ca.src[2] = wk;    ca.dst[2] = wqkv + (size_t)2048 * 2048; ca.n[2] = (long)512 * 2048;
  ca.src[3] = wv;    ca.dst[3] = wqkv + (size_t)2560 * 2048; ca.n[3] = (long)512 * 2048;
  ca.src[4] = wo;    ca.dst[4] = wob;                       ca.n[4] = (long)2048 * 2048;
  hipLaunchKernelGGL(cvt5_kernel, dim3(2048), dim3(256), 0, stream, ca);

  // fused QKV projection: qkv = xb @ wqkv^T  (M=4096, N=3072, K=2048), full-chip grid
  hipLaunchKernelGGL(gemmQ192, dim3(16, 16), dim3(512), 114688,
                     stream, xb, wqkv, qkv);

  // K-RoPE in place + V transpose
  hipLaunchKernelGGL(ropekv_kernel, dim3(16, 8, 4), dim3(256), 0, stream,
                     qkv, fcos, fsin, vtb);

  // flash attention (Q-RoPE fused, scale folded) -> ob (b,t,h,d) bf16
  hipLaunchKernelGGL(attn_kernel, dim3(16, 8, 4), dim3(512), 0, stream,
                     qkv, vtb, fcos, fsin, ob);

  // output projection: out = ob @ wob^T  (M=4096, N=2048, K=2048), fp32 out
  hipLaunchKernelGGL((gemm8p<true, 128, 16, 16>), dim3(16, 16), dim3(512), 98304,
                     stream, ob, wob, (void*)out, 2048);
}